// Round 2
// baseline (1212.474 us; speedup 1.0000x reference)
//
#include <hip/hip_runtime.h>
#include <hip/hip_bf16.h>

typedef __hip_bfloat16 bf16;
#define DEV static __device__ __forceinline__

DEV float b2f(bf16 v) { return __bfloat162float(v); }
DEV bf16 f2b(float v) { return __float2bfloat16(v); }
DEV float u2f(unsigned short u) { return __uint_as_float(((unsigned int)u) << 16); }
DEV float gelu(float x) { return 0.5f * x * (1.0f + erff(x * 0.70710678118654752f)); }

// Problem constants
#define BB 64
#define NT 139     // 1 + T + G1
#define DD 384
#define TT 10
#define HH 6
#define GG 138     // G1 + T
#define M1 8896    // BB*NT
#define MG 8832    // BB*GG
#define NGRP 2048  // BB*S
#define SCALE 0.125f

// Workspace byte offsets (256-aligned; lifetimes verified)
// XC   f32 8896x384  live whole call
// VIS  f32 2048x384
// XNB  bf16 8896x384 (LN1/LN2/LN3 out; dead after consuming GEMM)
// XFN  f32 8896x384  (attn1 o -> proj A; fc2 out; later x_prop)
// T16  f32 8896x16
// BIG1 bf16 8896x1152 (qkv s1; qkv1 s2)
// BIG2 bf16 8896x1536 (fc1h) / bf16 32768x384 (o1) / f32 8896x384 (x_final)
// ATT  bf16 32768x384 overlays XNB..BIG1 (all dead during proj1/groupmax)
#define XC_OFF   0UL
#define VIS_OFF  13664256UL
#define XNB_OFF  16809984UL
#define XFN_OFF  23642112UL
#define T16_OFF  37306368UL
#define BIG1_OFF 37875712UL
#define BIG2_OFF 58372096UL
#define ATT_OFF  XNB_OFF
// total ws demand: 85,700,608 bytes

#define OUT_X 3170304  // 64*129*384

DEV float4 ld4(const float* p) { return *(const float4*)p; }
DEV float4 ld4(const bf16* p) {
    ushort4 u = *(const ushort4*)p;
    return make_float4(u2f(u.x), u2f(u.y), u2f(u.z), u2f(u.w));
}
DEV void stc(float* p, float v) { *p = v; }
DEV void stc(bf16* p, float v) { *p = f2b(v); }

// ---------- concat: xc = [x[:, :1], prompt, x[:, 1:]] ----------
__global__ __launch_bounds__(256) void k_build_xc(const float* __restrict__ x,
                                                  const float* __restrict__ pe,
                                                  float* __restrict__ xc) {
    int i = blockIdx.x * 256 + threadIdx.x;
    if (i >= M1 * DD) return;
    int d = i % DD, r = i / DD, n = r % NT, b = r / NT;
    float v;
    if (n == 0)        v = x[(b * 129) * DD + d];
    else if (n <= TT)  v = pe[(n - 1) * DD + d];
    else               v = x[(b * 129 + n - TT) * DD + d];
    xc[i] = v;
}

// ---------- layernorm f32 -> bf16 (mode 1: gather row (r/138)*139+1+(r%138)) ----------
__global__ __launch_bounds__(128) void k_layernorm(const float* __restrict__ src, bf16* __restrict__ dst,
                                                   const float* __restrict__ g, const float* __restrict__ bta,
                                                   int mode) {
    int r = blockIdx.x;
    int srow = r;
    if (mode) srow = (r / GG) * NT + 1 + (r % GG);
    const float* p = src + (size_t)srow * DD;
    int t = threadIdx.x;
    float v0 = p[t], v1 = p[t + 128], v2 = p[t + 256];
    __shared__ float red[4];
    float s = v0 + v1 + v2;
    for (int off = 32; off; off >>= 1) s += __shfl_down(s, off, 64);
    if ((t & 63) == 0) red[t >> 6] = s;
    __syncthreads();
    float mean = (red[0] + red[1]) * (1.0f / 384.0f);
    float d0 = v0 - mean, d1 = v1 - mean, d2 = v2 - mean;
    float s2 = d0 * d0 + d1 * d1 + d2 * d2;
    for (int off = 32; off; off >>= 1) s2 += __shfl_down(s2, off, 64);
    if ((t & 63) == 0) red[2 + (t >> 6)] = s2;
    __syncthreads();
    float rstd = rsqrtf((red[2] + red[3]) * (1.0f / 384.0f) + 1e-5f);
    bf16* q = dst + (size_t)r * DD;
    q[t]       = f2b(d0 * rstd * g[t]       + bta[t]);
    q[t + 128] = f2b(d1 * rstd * g[t + 128] + bta[t + 128]);
    q[t + 256] = f2b(d2 * rstd * g[t + 256] + bta[t + 256]);
}

// ---------- generic GEMM: C[M,N] = act(A[M,K] @ W[N,K]^T + bias) (+res) ----------
#define BM 64
#define BN 64
#define BKK 16
template <typename TA, typename TC>
__global__ __launch_bounds__(256) void k_gemm(const TA* __restrict__ A, const float* __restrict__ W,
                                              const float* __restrict__ bias, const float* __restrict__ res,
                                              TC* __restrict__ C, int M, int N, int K, int act) {
    __shared__ float As[BKK][BM + 4];
    __shared__ float Ws[BKK][BN + 4];
    int t = threadIdx.x;
    int tx = t & 15, ty = t >> 4;
    int m0 = blockIdx.y * BM, n0 = blockIdx.x * BN;
    int lr = t >> 2;
    int lk = (t & 3) * 4;
    float acc[4][4] = {};
    for (int k0 = 0; k0 < K; k0 += BKK) {
        float4 av = ld4(A + (size_t)(m0 + lr) * K + k0 + lk);
        As[lk + 0][lr] = av.x; As[lk + 1][lr] = av.y;
        As[lk + 2][lr] = av.z; As[lk + 3][lr] = av.w;
        int wr = n0 + lr;
        float4 wv = make_float4(0.f, 0.f, 0.f, 0.f);
        if (wr < N) wv = ld4(W + (size_t)wr * K + k0 + lk);
        Ws[lk + 0][lr] = wv.x; Ws[lk + 1][lr] = wv.y;
        Ws[lk + 2][lr] = wv.z; Ws[lk + 3][lr] = wv.w;
        __syncthreads();
#pragma unroll
        for (int k = 0; k < BKK; ++k) {
            float a0 = As[k][ty * 4 + 0], a1 = As[k][ty * 4 + 1];
            float a2 = As[k][ty * 4 + 2], a3 = As[k][ty * 4 + 3];
            float b0 = Ws[k][tx * 4 + 0], b1 = Ws[k][tx * 4 + 1];
            float b2 = Ws[k][tx * 4 + 2], b3 = Ws[k][tx * 4 + 3];
            acc[0][0] += a0 * b0; acc[0][1] += a0 * b1; acc[0][2] += a0 * b2; acc[0][3] += a0 * b3;
            acc[1][0] += a1 * b0; acc[1][1] += a1 * b1; acc[1][2] += a1 * b2; acc[1][3] += a1 * b3;
            acc[2][0] += a2 * b0; acc[2][1] += a2 * b1; acc[2][2] += a2 * b2; acc[2][3] += a2 * b3;
            acc[3][0] += a3 * b0; acc[3][1] += a3 * b1; acc[3][2] += a3 * b2; acc[3][3] += a3 * b3;
        }
        __syncthreads();
    }
#pragma unroll
    for (int i = 0; i < 4; ++i) {
        int m = m0 + ty * 4 + i;
        size_t ro = (size_t)m * N;
#pragma unroll
        for (int j = 0; j < 4; ++j) {
            int n = n0 + tx * 4 + j;
            if (n < N) {
                float c = acc[i][j];
                if (bias) c += bias[n];
                if (act == 1) c = gelu(c);
                if (res) c += res[ro + n];
                stc(&C[ro + n], c);
            }
        }
    }
}

// ---------- stage-1 attention: one block per (b,h); attn probs (f32 out) + o (f32) ----------
__global__ __launch_bounds__(256) void k_attn1(const bf16* __restrict__ qkv, float* __restrict__ o,
                                               float* __restrict__ attn_out) {
    int bh = blockIdx.x;
    int b = bh / HH, h = bh % HH;
    __shared__ bf16 Kl[NT][68];
    __shared__ bf16 Vl[NT][68];
    __shared__ float Pl[4][NT + 1];
    int t = threadIdx.x;
    size_t base = (size_t)b * NT * 1152;
    for (int i = t; i < NT * 16; i += 256) {
        int n = i >> 4, d4 = (i & 15) * 4;
        *(ushort4*)&Kl[n][d4] = *(const ushort4*)(qkv + base + n * 1152 + 384 + h * 64 + d4);
        *(ushort4*)&Vl[n][d4] = *(const ushort4*)(qkv + base + n * 1152 + 768 + h * 64 + d4);
    }
    __syncthreads();
    int w = t >> 6, lane = t & 63;
    for (int n = w; n < NT; n += 4) {
        float qreg = b2f(qkv[base + n * 1152 + h * 64 + lane]);
        int m0 = lane, m1 = lane + 64, m2 = lane + 128;
        bool v2 = (m2 < NT);
        int m2c = v2 ? m2 : 0;
        float s0 = 0.f, s1 = 0.f, s2 = 0.f;
#pragma unroll 8
        for (int d = 0; d < 64; ++d) {
            float qv = __shfl(qreg, d, 64);
            s0 += qv * b2f(Kl[m0][d]);
            s1 += qv * b2f(Kl[m1][d]);
            s2 += qv * b2f(Kl[m2c][d]);
        }
        s0 *= SCALE; s1 *= SCALE; s2 *= SCALE;
        if (!v2) s2 = -INFINITY;
        float mx = fmaxf(fmaxf(s0, s1), s2);
        for (int off = 32; off; off >>= 1) mx = fmaxf(mx, __shfl_xor(mx, off, 64));
        float e0 = expf(s0 - mx), e1 = expf(s1 - mx), e2 = v2 ? expf(s2 - mx) : 0.f;
        float sm = e0 + e1 + e2;
        for (int off = 32; off; off >>= 1) sm += __shfl_xor(sm, off, 64);
        float inv = 1.0f / sm;
        float p0 = e0 * inv, p1 = e1 * inv, p2 = e2 * inv;
        size_t ab = ((size_t)(b * HH + h) * NT + n) * NT;
        attn_out[ab + m0] = p0;
        attn_out[ab + m1] = p1;
        if (v2) attn_out[ab + m2] = p2;
        Pl[w][m0] = p0; Pl[w][m1] = p1;
        if (v2) Pl[w][m2] = p2;
        float acc = 0.f;
#pragma unroll 8
        for (int m = 0; m < NT; ++m) acc += Pl[w][m] * b2f(Vl[m][lane]);
        o[((size_t)(b * NT + n)) * DD + h * 64 + lane] = acc;
    }
}

// ---------- stage-2 per-group attention: gather bf16 qkv1 rows; o1 bf16 ----------
#define SSTR 1160
__global__ __launch_bounds__(256) void k_attn2(const bf16* __restrict__ qkv, const int* __restrict__ idx,
                                               bf16* __restrict__ o1) {
    int g = blockIdx.x;
    __shared__ bf16 S[16][SSTR];
    __shared__ float Pl[16][17];
    __shared__ int ridx[16];
    int t = threadIdx.x;
    if (t < 16) ridx[t] = idx[g * 16 + t];
    __syncthreads();
    for (int i = t; i < 16 * 288; i += 256) {
        int j = i / 288, c4 = (i - j * 288) * 4;
        *(ushort4*)&S[j][c4] = *(const ushort4*)(qkv + (size_t)ridx[j] * 1152 + c4);
    }
    __syncthreads();
    int q = t >> 4, kk = t & 15;
    int wq = t >> 6, d = t & 63;
    for (int h = 0; h < HH; ++h) {
        const bf16* qa = &S[q][h * 64];
        const bf16* ka = &S[kk][384 + h * 64];
        float s = 0.f;
#pragma unroll 8
        for (int dd = 0; dd < 64; ++dd) s += b2f(qa[dd]) * b2f(ka[dd]);
        s *= SCALE;
        float mx = s;
        for (int off = 8; off; off >>= 1) mx = fmaxf(mx, __shfl_xor(mx, off, 64));
        float e = expf(s - mx), sm = e;
        for (int off = 8; off; off >>= 1) sm += __shfl_xor(sm, off, 64);
        Pl[q][kk] = e / sm;
        __syncthreads();
#pragma unroll
        for (int i = 0; i < 4; ++i) {
            int qv = wq + i * 4;
            float acc = 0.f;
#pragma unroll
            for (int k2 = 0; k2 < 16; ++k2) acc += Pl[qv][k2] * b2f(S[k2][768 + h * 64 + d]);
            o1[((size_t)(g * 16 + qv)) * DD + h * 64 + d] = f2b(acc);
        }
        __syncthreads();
    }
}

// ---------- adapter combine: xc += 0.7*(t16 @ up^T + up_b) + xfn ----------
__global__ __launch_bounds__(128) void k_ad_combine(const float* __restrict__ t16, const float* __restrict__ upw,
                                                    const float* __restrict__ upb, const float* __restrict__ xfn,
                                                    float* xc) {
    int r = blockIdx.x, t = threadIdx.x;
    __shared__ float tl[16];
    if (t < 16) tl[t] = t16[r * 16 + t];
    __syncthreads();
    for (int d = t; d < DD; d += 128) {
        float acc = 0.f;
#pragma unroll
        for (int c = 0; c < 4; ++c) {
            float4 u = *(const float4*)(upw + d * 16 + c * 4);
            acc += tl[c * 4 + 0] * u.x + tl[c * 4 + 1] * u.y
                 + tl[c * 4 + 2] * u.z + tl[c * 4 + 3] * u.w;
        }
        acc += upb[d];
        size_t i = (size_t)r * DD + d;
        xc[i] += 0.7f * acc + xfn[i];
    }
}

// ---------- group residual + max + BN + GELU + centers -> vis ----------
__global__ __launch_bounds__(128) void k_groupmax(const bf16* __restrict__ att, const float* __restrict__ xc,
                                                  const int* __restrict__ idx, const int* __restrict__ cidx,
                                                  const float* __restrict__ bg, const float* __restrict__ bb,
                                                  const float* __restrict__ bmean, const float* __restrict__ bvar,
                                                  float* __restrict__ vis) {
    int g = blockIdx.x, t = threadIdx.x;
    __shared__ int rows[16];
    __shared__ int crow;
    if (t < 16) { int r = idx[g * 16 + t]; rows[t] = (r / GG) * NT + 1 + (r % GG); }
    if (t == 16) { int r = cidx[g]; crow = (r / GG) * NT + 1 + (r % GG); }
    __syncthreads();
    for (int d = t; d < DD; d += 128) {
        float m = -INFINITY;
#pragma unroll
        for (int j = 0; j < 16; ++j) {
            float v = b2f(att[((size_t)(g * 16 + j)) * DD + d]) + xc[(size_t)rows[j] * DD + d];
            m = fmaxf(m, v);
        }
        float bn = (m - bmean[d]) * rsqrtf(bvar[d] + 1e-5f) * bg[d] + bb[d];
        bn = gelu(bn);
        vis[(size_t)g * DD + d] = bn + 0.3f * xc[(size_t)crow * DD + d];
    }
}

// ---------- propagate ----------
__global__ __launch_bounds__(128) void k_propagate(const float* __restrict__ c1, const float* __restrict__ c2,
                                                   const float* __restrict__ xc, const float* __restrict__ vis,
                                                   float* __restrict__ xp) {
    int blk = blockIdx.x;
    int b = blk >> 7, i = blk & 127;
    int t = threadIdx.x;
    __shared__ float wl[32];
    __shared__ float wsum;
    if (t < 32) {
        float dx = c1[(b * 128 + i) * 3 + 0] - c2[(b * 32 + t) * 3 + 0];
        float dy = c1[(b * 128 + i) * 3 + 1] - c2[(b * 32 + t) * 3 + 1];
        float dz = c1[(b * 128 + i) * 3 + 2] - c2[(b * 32 + t) * 3 + 2];
        wl[t] = 1.0f / (dx * dx + dy * dy + dz * dz + 1e-8f);
    }
    __syncthreads();
    if (t == 0) {
        float s = 0.f;
        for (int j = 0; j < 32; ++j) s += wl[j];
        wsum = s;
    }
    __syncthreads();
    float sc = 0.3f / wsum;
    for (int d = t; d < DD; d += 128) {
        float acc = 0.f;
#pragma unroll 8
        for (int j = 0; j < 32; ++j) acc += wl[j] * vis[((size_t)(b * 32 + j)) * DD + d];
        xp[((size_t)(b * 128 + i)) * DD + d] = xc[((size_t)(b * NT + 11 + i)) * DD + d] + sc * acc;
    }
}

// ---------- build x_final = [cls, prompt, x_prop] ----------
__global__ __launch_bounds__(256) void k_build_xfinal(const float* __restrict__ xc, const float* __restrict__ xp,
                                                      float* __restrict__ xf) {
    int i = blockIdx.x * 256 + threadIdx.x;
    if (i >= M1 * DD) return;
    int d = i % DD, r = i / DD, n = r % NT, b = r / NT;
    xf[i] = (n < 11) ? xc[i] : xp[((size_t)(b * 128 + n - 11)) * DD + d];
}

// ---------- final adapter-up + residual + slice -> f32 out ----------
__global__ __launch_bounds__(128) void k_final(const float* __restrict__ t16, const float* __restrict__ upw,
                                               const float* __restrict__ upb, const float* __restrict__ xf,
                                               float* __restrict__ outx) {
    int rb = blockIdx.x, t = threadIdx.x;
    int b = rb / 129, no = rb % 129;
    int src = b * NT + (no == 0 ? 0 : no + TT);
    __shared__ float tl[16];
    if (t < 16) tl[t] = t16[src * 16 + t];
    __syncthreads();
    for (int d = t; d < DD; d += 128) {
        float acc = 0.f;
#pragma unroll
        for (int c = 0; c < 4; ++c) {
            float4 u = *(const float4*)(upw + d * 16 + c * 4);
            acc += tl[c * 4 + 0] * u.x + tl[c * 4 + 1] * u.y
                 + tl[c * 4 + 2] * u.z + tl[c * 4 + 3] * u.w;
        }
        acc += upb[d];
        outx[(size_t)rb * DD + d] = acc + xf[(size_t)src * DD + d];
    }
}

extern "C" void kernel_launch(void* const* d_in, const int* in_sizes, int n_in,
                              void* d_out, int out_size, void* d_ws, size_t ws_size,
                              hipStream_t stream) {
    const float* x_in    = (const float*)d_in[0];
    const float* center1 = (const float*)d_in[2];
    const float* center2 = (const float*)d_in[3];
    const int*   idx     = (const int*)d_in[5];
    const int*   cidx    = (const int*)d_in[6];
    const float* ln1_g   = (const float*)d_in[9];
    const float* ln1_b   = (const float*)d_in[10];
    const float* ln2_g   = (const float*)d_in[11];
    const float* ln2_b   = (const float*)d_in[12];
    const float* qkv_w   = (const float*)d_in[13];
    const float* proj_w  = (const float*)d_in[14];
    const float* proj_b  = (const float*)d_in[15];
    const float* fc1_w   = (const float*)d_in[16];
    const float* fc1_b   = (const float*)d_in[17];
    const float* fc2_w   = (const float*)d_in[18];
    const float* fc2_b   = (const float*)d_in[19];
    const float* ad_dw   = (const float*)d_in[20];
    const float* ad_db   = (const float*)d_in[21];
    const float* ad_uw   = (const float*)d_in[22];
    const float* ad_ub   = (const float*)d_in[23];
    const float* ad1_dw  = (const float*)d_in[24];
    const float* ad1_db  = (const float*)d_in[25];
    const float* ad1_uw  = (const float*)d_in[26];
    const float* ad1_ub  = (const float*)d_in[27];
    const float* prompt  = (const float*)d_in[28];
    const float* bn_g    = (const float*)d_in[29];
    const float* bn_b    = (const float*)d_in[30];
    const float* bn_mean = (const float*)d_in[31];
    const float* bn_var  = (const float*)d_in[32];
    const float* qkv1_w  = (const float*)d_in[33];
    const float* proj1_w = (const float*)d_in[34];
    const float* proj1_b = (const float*)d_in[35];
    const float* ln3_g   = (const float*)d_in[36];
    const float* ln3_b   = (const float*)d_in[37];

    char* wsb = (char*)d_ws;
    float* XC  = (float*)(wsb + XC_OFF);
    float* VIS = (float*)(wsb + VIS_OFF);
    bf16*  XNB = (bf16*)(wsb + XNB_OFF);
    float* XFN = (float*)(wsb + XFN_OFF);
    float* T16 = (float*)(wsb + T16_OFF);
    bf16*  BIG1 = (bf16*)(wsb + BIG1_OFF);
    bf16*  BIG2 = (bf16*)(wsb + BIG2_OFF);
    float* XFIN = (float*)(wsb + BIG2_OFF);
    bf16*  ATT = (bf16*)(wsb + ATT_OFF);

    float* out_x    = (float*)d_out;
    float* out_attn = out_x + OUT_X;

    // --- stage 1 ---
    k_build_xc<<<(M1 * DD + 255) / 256, 256, 0, stream>>>(x_in, prompt, XC);
    k_layernorm<<<M1, 128, 0, stream>>>(XC, XNB, ln1_g, ln1_b, 0);
    k_gemm<<<dim3(18, 139), 256, 0, stream>>>(XNB, qkv_w, (const float*)nullptr, (const float*)nullptr, BIG1, M1, 1152, 384, 0);
    k_attn1<<<BB * HH, 256, 0, stream>>>(BIG1, XFN, out_attn);
    k_gemm<<<dim3(6, 139), 256, 0, stream>>>(XFN, proj_w, proj_b, XC, XC, M1, 384, 384, 0);
    k_layernorm<<<M1, 128, 0, stream>>>(XC, XNB, ln2_g, ln2_b, 0);
    k_gemm<<<dim3(24, 139), 256, 0, stream>>>(XNB, fc1_w, fc1_b, (const float*)nullptr, BIG2, M1, 1536, 384, 1);
    k_gemm<<<dim3(6, 139), 256, 0, stream>>>(BIG2, fc2_w, fc2_b, (const float*)nullptr, XFN, M1, 384, 1536, 0);
    k_gemm<<<dim3(1, 139), 256, 0, stream>>>(XFN, ad_dw, ad_db, (const float*)nullptr, T16, M1, 16, 384, 1);
    k_ad_combine<<<M1, 128, 0, stream>>>(T16, ad_uw, ad_ub, XFN, XC);

    // --- stage 2 (group attention on 8832 unique rows) ---
    k_layernorm<<<MG, 128, 0, stream>>>(XC, XNB, ln3_g, ln3_b, 1);
    k_gemm<<<dim3(18, 138), 256, 0, stream>>>(XNB, qkv1_w, (const float*)nullptr, (const float*)nullptr, BIG1, MG, 1152, 384, 0);
    k_attn2<<<NGRP, 256, 0, stream>>>(BIG1, idx, BIG2);
    k_gemm<<<dim3(6, 512), 256, 0, stream>>>(BIG2, proj1_w, proj1_b, (const float*)nullptr, ATT, NGRP * 16, 384, 384, 0);
    k_groupmax<<<NGRP, 128, 0, stream>>>(ATT, XC, idx, cidx, bn_g, bn_b, bn_mean, bn_var, VIS);
    k_propagate<<<BB * 128, 128, 0, stream>>>(center1, center2, XC, VIS, XFN);

    // --- final adapter + slice ---
    k_build_xfinal<<<(M1 * DD + 255) / 256, 256, 0, stream>>>(XC, XFN, XFIN);
    k_gemm<<<dim3(1, 139), 256, 0, stream>>>(XFIN, ad1_dw, ad1_db, (const float*)nullptr, T16, M1, 16, 384, 1);
    k_final<<<BB * 129, 128, 0, stream>>>(T16, ad1_uw, ad1_ub, XFIN, out_x);
}

// Round 3
// 730.456 us; speedup vs baseline: 1.6599x; 1.6599x over previous
//
#include <hip/hip_runtime.h>
#include <hip/hip_bf16.h>

typedef __hip_bfloat16 bf16;
typedef __attribute__((ext_vector_type(8))) short short8;
typedef __attribute__((ext_vector_type(4))) float f32x4;

#define DEV static __device__ __forceinline__

DEV float b2f(bf16 v) { return __bfloat162float(v); }
DEV bf16 f2b(float v) { return __float2bfloat16(v); }
DEV float u2f(unsigned short u) { return __uint_as_float(((unsigned int)u) << 16); }
DEV float gelu(float x) { return 0.5f * x * (1.0f + erff(x * 0.70710678118654752f)); }

// Problem constants
#define BB 64
#define NT 139     // 1 + T + G1
#define DD 384
#define TT 10
#define HH 6
#define GG 138     // G1 + T
#define M1 8896    // BB*NT
#define MG 8832    // BB*GG
#define NGRP 2048  // BB*S
#define SCALE 0.125f

// Workspace byte offsets (same proven layout as round 2; ws demand 85.7 MB)
#define XC_OFF   0UL          // f32 8896x384 residual stream, live whole call
#define VIS_OFF  13664256UL   // f32 2048x384
#define XNB_OFF  16809984UL   // bf16 8896x384: LN out; attn1 o; dead after consumer
#define XFN_OFF  23642112UL   // f32 8896x384: fc2 out; x_prop
#define T16_OFF  37306368UL   // f32 8896x16
#define BIG1_OFF 37875712UL   // bf16 8896x1152: qkv / qkv1
#define BIG2_OFF 58372096UL   // bf16 8896x1536 fc1h / bf16 32768x384 o1 / f32 x_final
#define ATT_OFF  XNB_OFF      // bf16 32768x384 proj1 out (overlays dead XNB..BIG1 prefix)

#define OUT_X 3170304  // 64*129*384

DEV float4 ld4(const float* p) { return *(const float4*)p; }
DEV float4 ld4(const bf16* p) {
    ushort4 u = *(const ushort4*)p;
    return make_float4(u2f(u.x), u2f(u.y), u2f(u.z), u2f(u.w));
}
DEV void stc(float* p, float v) { *p = v; }
DEV void stc(bf16* p, float v) { *p = f2b(v); }

// ---------- concat: xc = [x[:, :1], prompt, x[:, 1:]] ----------
__global__ __launch_bounds__(256) void k_build_xc(const float* __restrict__ x,
                                                  const float* __restrict__ pe,
                                                  float* __restrict__ xc) {
    int i = blockIdx.x * 256 + threadIdx.x;
    if (i >= M1 * DD) return;
    int d = i % DD, r = i / DD, n = r % NT, b = r / NT;
    float v;
    if (n == 0)        v = x[(b * 129) * DD + d];
    else if (n <= TT)  v = pe[(n - 1) * DD + d];
    else               v = x[(b * 129 + n - TT) * DD + d];
    xc[i] = v;
}

// ---------- layernorm f32 -> bf16 (mode 1: gather row (r/138)*139+1+(r%138)) ----------
__global__ __launch_bounds__(128) void k_layernorm(const float* __restrict__ src, bf16* __restrict__ dst,
                                                   const float* __restrict__ g, const float* __restrict__ bta,
                                                   int mode) {
    int r = blockIdx.x;
    int srow = r;
    if (mode) srow = (r / GG) * NT + 1 + (r % GG);
    const float* p = src + (size_t)srow * DD;
    int t = threadIdx.x;
    float v0 = p[t], v1 = p[t + 128], v2 = p[t + 256];
    __shared__ float red[4];
    float s = v0 + v1 + v2;
    for (int off = 32; off; off >>= 1) s += __shfl_down(s, off, 64);
    if ((t & 63) == 0) red[t >> 6] = s;
    __syncthreads();
    float mean = (red[0] + red[1]) * (1.0f / 384.0f);
    float d0 = v0 - mean, d1 = v1 - mean, d2 = v2 - mean;
    float s2 = d0 * d0 + d1 * d1 + d2 * d2;
    for (int off = 32; off; off >>= 1) s2 += __shfl_down(s2, off, 64);
    if ((t & 63) == 0) red[2 + (t >> 6)] = s2;
    __syncthreads();
    float rstd = rsqrtf((red[2] + red[3]) * (1.0f / 384.0f) + 1e-5f);
    bf16* q = dst + (size_t)r * DD;
    q[t]       = f2b(d0 * rstd * g[t]       + bta[t]);
    q[t + 128] = f2b(d1 * rstd * g[t + 128] + bta[t + 128]);
    q[t + 256] = f2b(d2 * rstd * g[t + 256] + bta[t + 256]);
}

// ---------- MFMA GEMM: C[M,N] = act(A[M,K]bf16 @ W[N,K]^T f32 + bias) (+res) ----------
// 128x128 block tile, 4 waves -> 64x64 each (4x4 of 16x16x32 MFMAs), BK=32.
// N, K multiples of 128/32; M guarded (clamped loads, guarded stores).
template <typename TC>
__global__ __launch_bounds__(256) void mf_gemm(const bf16* __restrict__ A, const float* __restrict__ W,
                                               const float* __restrict__ bias, const float* __restrict__ res,
                                               TC* __restrict__ C, int M, int N, int K, int act) {
    __shared__ bf16 As[128][40];
    __shared__ bf16 Ws[128][40];
    int t = threadIdx.x;
    int m0 = blockIdx.y * 128, n0 = blockIdx.x * 128;
    int lane = t & 63, wv = t >> 6;
    int wm = (wv >> 1) * 64, wn = (wv & 1) * 64;
    int fr = lane & 15, fq = lane >> 4;   // frag row / k-quad
    int ar = t >> 2, ac = (t & 3) * 8;    // A staging: 4 thr/row, 8 bf16 each
    int wr = t >> 3, wc = (t & 7) * 4;    // W staging: 8 thr/row, 4 f32 each
    f32x4 acc[4][4] = {};
    for (int k0 = 0; k0 < K; k0 += 32) {
#pragma unroll
        for (int p = 0; p < 2; ++p) {
            int row = p * 64 + ar;
            int gr = m0 + row; if (gr >= M) gr = M - 1;
            *(uint4*)&As[row][ac] = *(const uint4*)(A + (size_t)gr * K + k0 + ac);
        }
#pragma unroll
        for (int p = 0; p < 4; ++p) {
            int row = p * 32 + wr;
            float4 wvv = *(const float4*)(W + (size_t)(n0 + row) * K + k0 + wc);
            ushort4 u;
            u.x = (unsigned short)(((unsigned int)__builtin_bit_cast(unsigned int, b2f(f2b(wvv.x)))) >> 16);
            // round-to-nearest via f2b, then pack:
            bf16 c0 = f2b(wvv.x), c1 = f2b(wvv.y), c2 = f2b(wvv.z), c3 = f2b(wvv.w);
            Ws[row][wc + 0] = c0; Ws[row][wc + 1] = c1;
            Ws[row][wc + 2] = c2; Ws[row][wc + 3] = c3;
        }
        __syncthreads();
        short8 af[4], bf[4];
#pragma unroll
        for (int i = 0; i < 4; ++i) af[i] = *(const short8*)&As[wm + i * 16 + fr][fq * 8];
#pragma unroll
        for (int j = 0; j < 4; ++j) bf[j] = *(const short8*)&Ws[wn + j * 16 + fr][fq * 8];
#pragma unroll
        for (int i = 0; i < 4; ++i)
#pragma unroll
            for (int j = 0; j < 4; ++j)
                acc[i][j] = __builtin_amdgcn_mfma_f32_16x16x32_bf16(af[i], bf[j], acc[i][j], 0, 0, 0);
        __syncthreads();
    }
#pragma unroll
    for (int i = 0; i < 4; ++i) {
#pragma unroll
        for (int r = 0; r < 4; ++r) {
            int row = m0 + wm + i * 16 + fq * 4 + r;
            if (row < M) {
                size_t ro = (size_t)row * N;
#pragma unroll
                for (int j = 0; j < 4; ++j) {
                    int col = n0 + wn + j * 16 + fr;
                    float c = acc[i][j][r];
                    if (bias) c += bias[col];
                    if (act == 1) c = gelu(c);
                    if (res) c += res[ro + col];
                    stc(&C[ro + col], c);
                }
            }
        }
    }
}

// ---------- small fp32 GEMM (N=16 adapters): C[M,N] = gelu(A @ W^T + b) ----------
#define BM 64
#define BN 64
#define BKK 16
template <typename TA, typename TC>
__global__ __launch_bounds__(256) void k_gemm(const TA* __restrict__ A, const float* __restrict__ W,
                                              const float* __restrict__ bias, const float* __restrict__ res,
                                              TC* __restrict__ C, int M, int N, int K, int act) {
    __shared__ float As[BKK][BM + 4];
    __shared__ float Wsm[BKK][BN + 4];
    int t = threadIdx.x;
    int tx = t & 15, ty = t >> 4;
    int m0 = blockIdx.y * BM, n0 = blockIdx.x * BN;
    int lr = t >> 2;
    int lk = (t & 3) * 4;
    float acc[4][4] = {};
    for (int k0 = 0; k0 < K; k0 += BKK) {
        float4 av = ld4(A + (size_t)(m0 + lr) * K + k0 + lk);
        As[lk + 0][lr] = av.x; As[lk + 1][lr] = av.y;
        As[lk + 2][lr] = av.z; As[lk + 3][lr] = av.w;
        int wrr = n0 + lr;
        float4 wv = make_float4(0.f, 0.f, 0.f, 0.f);
        if (wrr < N) wv = ld4(W + (size_t)wrr * K + k0 + lk);
        Wsm[lk + 0][lr] = wv.x; Wsm[lk + 1][lr] = wv.y;
        Wsm[lk + 2][lr] = wv.z; Wsm[lk + 3][lr] = wv.w;
        __syncthreads();
#pragma unroll
        for (int k = 0; k < BKK; ++k) {
            float a0 = As[k][ty * 4 + 0], a1 = As[k][ty * 4 + 1];
            float a2 = As[k][ty * 4 + 2], a3 = As[k][ty * 4 + 3];
            float b0 = Wsm[k][tx * 4 + 0], b1 = Wsm[k][tx * 4 + 1];
            float b2 = Wsm[k][tx * 4 + 2], b3 = Wsm[k][tx * 4 + 3];
            acc[0][0] += a0 * b0; acc[0][1] += a0 * b1; acc[0][2] += a0 * b2; acc[0][3] += a0 * b3;
            acc[1][0] += a1 * b0; acc[1][1] += a1 * b1; acc[1][2] += a1 * b2; acc[1][3] += a1 * b3;
            acc[2][0] += a2 * b0; acc[2][1] += a2 * b1; acc[2][2] += a2 * b2; acc[2][3] += a2 * b3;
            acc[3][0] += a3 * b0; acc[3][1] += a3 * b1; acc[3][2] += a3 * b2; acc[3][3] += a3 * b3;
        }
        __syncthreads();
    }
#pragma unroll
    for (int i = 0; i < 4; ++i) {
        int m = m0 + ty * 4 + i;
        size_t ro = (size_t)m * N;
#pragma unroll
        for (int j = 0; j < 4; ++j) {
            int n = n0 + tx * 4 + j;
            if (n < N) {
                float c = acc[i][j];
                if (bias) c += bias[n];
                if (act == 1) c = gelu(c);
                if (res) c += res[ro + n];
                stc(&C[ro + n], c);
            }
        }
    }
}

// ---------- stage-1 attention: block = (b,h) x slice of 35 rows; o -> bf16 ----------
__global__ __launch_bounds__(256) void k_attn1(const bf16* __restrict__ qkv, bf16* __restrict__ o,
                                               float* __restrict__ attn_out) {
    int bh = blockIdx.x;
    int b = bh / HH, h = bh % HH;
    int start = blockIdx.y * 35;
    int end = start + 35; if (end > NT) end = NT;
    __shared__ bf16 Kl[NT][68];
    __shared__ bf16 Vl[NT][68];
    __shared__ float Pl[4][NT + 1];
    int t = threadIdx.x;
    size_t base = (size_t)b * NT * 1152;
    for (int i = t; i < NT * 16; i += 256) {
        int n = i >> 4, d4 = (i & 15) * 4;
        *(ushort4*)&Kl[n][d4] = *(const ushort4*)(qkv + base + n * 1152 + 384 + h * 64 + d4);
        *(ushort4*)&Vl[n][d4] = *(const ushort4*)(qkv + base + n * 1152 + 768 + h * 64 + d4);
    }
    __syncthreads();
    int w = t >> 6, lane = t & 63;
    for (int n = start + w; n < end; n += 4) {
        float qreg = b2f(qkv[base + n * 1152 + h * 64 + lane]);
        int m0 = lane, m1 = lane + 64, m2 = lane + 128;
        bool v2 = (m2 < NT);
        int m2c = v2 ? m2 : 0;
        float s0 = 0.f, s1 = 0.f, s2 = 0.f;
#pragma unroll 8
        for (int d = 0; d < 64; ++d) {
            float qv = __shfl(qreg, d, 64);
            s0 += qv * b2f(Kl[m0][d]);
            s1 += qv * b2f(Kl[m1][d]);
            s2 += qv * b2f(Kl[m2c][d]);
        }
        s0 *= SCALE; s1 *= SCALE; s2 *= SCALE;
        if (!v2) s2 = -INFINITY;
        float mx = fmaxf(fmaxf(s0, s1), s2);
        for (int off = 32; off; off >>= 1) mx = fmaxf(mx, __shfl_xor(mx, off, 64));
        float e0 = expf(s0 - mx), e1 = expf(s1 - mx), e2 = v2 ? expf(s2 - mx) : 0.f;
        float sm = e0 + e1 + e2;
        for (int off = 32; off; off >>= 1) sm += __shfl_xor(sm, off, 64);
        float inv = 1.0f / sm;
        float p0 = e0 * inv, p1 = e1 * inv, p2 = e2 * inv;
        size_t ab = ((size_t)(b * HH + h) * NT + n) * NT;
        attn_out[ab + m0] = p0;
        attn_out[ab + m1] = p1;
        if (v2) attn_out[ab + m2] = p2;
        Pl[w][m0] = p0; Pl[w][m1] = p1;
        if (v2) Pl[w][m2] = p2;
        float acc = 0.f;
#pragma unroll 8
        for (int m = 0; m < NT; ++m) acc += Pl[w][m] * b2f(Vl[m][lane]);
        o[((size_t)(b * NT + n)) * DD + h * 64 + lane] = f2b(acc);
    }
}

// ---------- stage-2 per-group attention ----------
#define SSTR 1160
__global__ __launch_bounds__(256) void k_attn2(const bf16* __restrict__ qkv, const int* __restrict__ idx,
                                               bf16* __restrict__ o1) {
    int g = blockIdx.x;
    __shared__ bf16 S[16][SSTR];
    __shared__ float Pl[16][17];
    __shared__ int ridx[16];
    int t = threadIdx.x;
    if (t < 16) ridx[t] = idx[g * 16 + t];
    __syncthreads();
    for (int i = t; i < 16 * 288; i += 256) {
        int j = i / 288, c4 = (i - j * 288) * 4;
        *(ushort4*)&S[j][c4] = *(const ushort4*)(qkv + (size_t)ridx[j] * 1152 + c4);
    }
    __syncthreads();
    int q = t >> 4, kk = t & 15;
    int wq = t >> 6, d = t & 63;
    for (int h = 0; h < HH; ++h) {
        const bf16* qa = &S[q][h * 64];
        const bf16* ka = &S[kk][384 + h * 64];
        float s = 0.f;
#pragma unroll 8
        for (int dd = 0; dd < 64; ++dd) s += b2f(qa[dd]) * b2f(ka[dd]);
        s *= SCALE;
        float mx = s;
        for (int off = 8; off; off >>= 1) mx = fmaxf(mx, __shfl_xor(mx, off, 64));
        float e = expf(s - mx), sm = e;
        for (int off = 8; off; off >>= 1) sm += __shfl_xor(sm, off, 64);
        Pl[q][kk] = e / sm;
        __syncthreads();
#pragma unroll
        for (int i = 0; i < 4; ++i) {
            int qv = wq + i * 4;
            float acc = 0.f;
#pragma unroll
            for (int k2 = 0; k2 < 16; ++k2) acc += Pl[qv][k2] * b2f(S[k2][768 + h * 64 + d]);
            o1[((size_t)(g * 16 + qv)) * DD + h * 64 + d] = f2b(acc);
        }
        __syncthreads();
    }
}

// ---------- adapter combine: xc += 0.7*(t16 @ up^T + up_b) + xfn ----------
__global__ __launch_bounds__(128) void k_ad_combine(const float* __restrict__ t16, const float* __restrict__ upw,
                                                    const float* __restrict__ upb, const float* __restrict__ xfn,
                                                    float* xc) {
    int r = blockIdx.x, t = threadIdx.x;
    __shared__ float tl[16];
    if (t < 16) tl[t] = t16[r * 16 + t];
    __syncthreads();
    for (int d = t; d < DD; d += 128) {
        float acc = 0.f;
#pragma unroll
        for (int c = 0; c < 4; ++c) {
            float4 u = *(const float4*)(upw + d * 16 + c * 4);
            acc += tl[c * 4 + 0] * u.x + tl[c * 4 + 1] * u.y
                 + tl[c * 4 + 2] * u.z + tl[c * 4 + 3] * u.w;
        }
        acc += upb[d];
        size_t i = (size_t)r * DD + d;
        xc[i] += 0.7f * acc + xfn[i];
    }
}

// ---------- group residual + max + BN + GELU + centers -> vis ----------
__global__ __launch_bounds__(128) void k_groupmax(const bf16* __restrict__ att, const float* __restrict__ xc,
                                                  const int* __restrict__ idx, const int* __restrict__ cidx,
                                                  const float* __restrict__ bg, const float* __restrict__ bb,
                                                  const float* __restrict__ bmean, const float* __restrict__ bvar,
                                                  float* __restrict__ vis) {
    int g = blockIdx.x, t = threadIdx.x;
    __shared__ int rows[16];
    __shared__ int crow;
    if (t < 16) { int r = idx[g * 16 + t]; rows[t] = (r / GG) * NT + 1 + (r % GG); }
    if (t == 16) { int r = cidx[g]; crow = (r / GG) * NT + 1 + (r % GG); }
    __syncthreads();
    for (int d = t; d < DD; d += 128) {
        float m = -INFINITY;
#pragma unroll
        for (int j = 0; j < 16; ++j) {
            float v = b2f(att[((size_t)(g * 16 + j)) * DD + d]) + xc[(size_t)rows[j] * DD + d];
            m = fmaxf(m, v);
        }
        float bn = (m - bmean[d]) * rsqrtf(bvar[d] + 1e-5f) * bg[d] + bb[d];
        bn = gelu(bn);
        vis[(size_t)g * DD + d] = bn + 0.3f * xc[(size_t)crow * DD + d];
    }
}

// ---------- propagate ----------
__global__ __launch_bounds__(128) void k_propagate(const float* __restrict__ c1, const float* __restrict__ c2,
                                                   const float* __restrict__ xc, const float* __restrict__ vis,
                                                   float* __restrict__ xp) {
    int blk = blockIdx.x;
    int b = blk >> 7, i = blk & 127;
    int t = threadIdx.x;
    __shared__ float wl[32];
    __shared__ float wsum;
    if (t < 32) {
        float dx = c1[(b * 128 + i) * 3 + 0] - c2[(b * 32 + t) * 3 + 0];
        float dy = c1[(b * 128 + i) * 3 + 1] - c2[(b * 32 + t) * 3 + 1];
        float dz = c1[(b * 128 + i) * 3 + 2] - c2[(b * 32 + t) * 3 + 2];
        wl[t] = 1.0f / (dx * dx + dy * dy + dz * dz + 1e-8f);
    }
    __syncthreads();
    if (t == 0) {
        float s = 0.f;
        for (int j = 0; j < 32; ++j) s += wl[j];
        wsum = s;
    }
    __syncthreads();
    float sc = 0.3f / wsum;
    for (int d = t; d < DD; d += 128) {
        float acc = 0.f;
#pragma unroll 8
        for (int j = 0; j < 32; ++j) acc += wl[j] * vis[((size_t)(b * 32 + j)) * DD + d];
        xp[((size_t)(b * 128 + i)) * DD + d] = xc[((size_t)(b * NT + 11 + i)) * DD + d] + sc * acc;
    }
}

// ---------- build x_final = [cls, prompt, x_prop] ----------
__global__ __launch_bounds__(256) void k_build_xfinal(const float* __restrict__ xc, const float* __restrict__ xp,
                                                      float* __restrict__ xf) {
    int i = blockIdx.x * 256 + threadIdx.x;
    if (i >= M1 * DD) return;
    int d = i % DD, r = i / DD, n = r % NT, b = r / NT;
    xf[i] = (n < 11) ? xc[i] : xp[((size_t)(b * 128 + n - 11)) * DD + d];
}

// ---------- final adapter-up + residual + slice -> f32 out ----------
__global__ __launch_bounds__(128) void k_final(const float* __restrict__ t16, const float* __restrict__ upw,
                                               const float* __restrict__ upb, const float* __restrict__ xf,
                                               float* __restrict__ outx) {
    int rb = blockIdx.x, t = threadIdx.x;
    int b = rb / 129, no = rb % 129;
    int src = b * NT + (no == 0 ? 0 : no + TT);
    __shared__ float tl[16];
    if (t < 16) tl[t] = t16[src * 16 + t];
    __syncthreads();
    for (int d = t; d < DD; d += 128) {
        float acc = 0.f;
#pragma unroll
        for (int c = 0; c < 4; ++c) {
            float4 u = *(const float4*)(upw + d * 16 + c * 4);
            acc += tl[c * 4 + 0] * u.x + tl[c * 4 + 1] * u.y
                 + tl[c * 4 + 2] * u.z + tl[c * 4 + 3] * u.w;
        }
        acc += upb[d];
        outx[(size_t)rb * DD + d] = acc + xf[(size_t)src * DD + d];
    }
}

extern "C" void kernel_launch(void* const* d_in, const int* in_sizes, int n_in,
                              void* d_out, int out_size, void* d_ws, size_t ws_size,
                              hipStream_t stream) {
    const float* x_in    = (const float*)d_in[0];
    const float* center1 = (const float*)d_in[2];
    const float* center2 = (const float*)d_in[3];
    const int*   idx     = (const int*)d_in[5];
    const int*   cidx    = (const int*)d_in[6];
    const float* ln1_g   = (const float*)d_in[9];
    const float* ln1_b   = (const float*)d_in[10];
    const float* ln2_g   = (const float*)d_in[11];
    const float* ln2_b   = (const float*)d_in[12];
    const float* qkv_w   = (const float*)d_in[13];
    const float* proj_w  = (const float*)d_in[14];
    const float* proj_b  = (const float*)d_in[15];
    const float* fc1_w   = (const float*)d_in[16];
    const float* fc1_b   = (const float*)d_in[17];
    const float* fc2_w   = (const float*)d_in[18];
    const float* fc2_b   = (const float*)d_in[19];
    const float* ad_dw   = (const float*)d_in[20];
    const float* ad_db   = (const float*)d_in[21];
    const float* ad_uw   = (const float*)d_in[22];
    const float* ad_ub   = (const float*)d_in[23];
    const float* ad1_dw  = (const float*)d_in[24];
    const float* ad1_db  = (const float*)d_in[25];
    const float* ad1_uw  = (const float*)d_in[26];
    const float* ad1_ub  = (const float*)d_in[27];
    const float* prompt  = (const float*)d_in[28];
    const float* bn_g    = (const float*)d_in[29];
    const float* bn_b    = (const float*)d_in[30];
    const float* bn_mean = (const float*)d_in[31];
    const float* bn_var  = (const float*)d_in[32];
    const float* qkv1_w  = (const float*)d_in[33];
    const float* proj1_w = (const float*)d_in[34];
    const float* proj1_b = (const float*)d_in[35];
    const float* ln3_g   = (const float*)d_in[36];
    const float* ln3_b   = (const float*)d_in[37];

    char* wsb = (char*)d_ws;
    float* XC   = (float*)(wsb + XC_OFF);
    float* VIS  = (float*)(wsb + VIS_OFF);
    bf16*  XNB  = (bf16*)(wsb + XNB_OFF);
    float* XFN  = (float*)(wsb + XFN_OFF);
    float* T16  = (float*)(wsb + T16_OFF);
    bf16*  BIG1 = (bf16*)(wsb + BIG1_OFF);
    bf16*  BIG2 = (bf16*)(wsb + BIG2_OFF);
    float* XFIN = (float*)(wsb + BIG2_OFF);
    bf16*  ATT  = (bf16*)(wsb + ATT_OFF);

    float* out_x    = (float*)d_out;
    float* out_attn = out_x + OUT_X;

    // --- stage 1 ---
    k_build_xc<<<(M1 * DD + 255) / 256, 256, 0, stream>>>(x_in, prompt, XC);
    k_layernorm<<<M1, 128, 0, stream>>>(XC, XNB, ln1_g, ln1_b, 0);
    mf_gemm<<<dim3(9, 70), 256, 0, stream>>>(XNB, qkv_w, (const float*)nullptr, (const float*)nullptr, BIG1, M1, 1152, 384, 0);
    k_attn1<<<dim3(BB * HH, 4), 256, 0, stream>>>(BIG1, XNB, out_attn);
    mf_gemm<<<dim3(3, 70), 256, 0, stream>>>(XNB, proj_w, proj_b, XC, XC, M1, 384, 384, 0);
    k_layernorm<<<M1, 128, 0, stream>>>(XC, XNB, ln2_g, ln2_b, 0);
    mf_gemm<<<dim3(12, 70), 256, 0, stream>>>(XNB, fc1_w, fc1_b, (const float*)nullptr, BIG2, M1, 1536, 384, 1);
    mf_gemm<<<dim3(3, 70), 256, 0, stream>>>(BIG2, fc2_w, fc2_b, (const float*)nullptr, XFN, M1, 384, 1536, 0);
    k_gemm<<<dim3(1, 139), 256, 0, stream>>>(XFN, ad_dw, ad_db, (const float*)nullptr, T16, M1, 16, 384, 1);
    k_ad_combine<<<M1, 128, 0, stream>>>(T16, ad_uw, ad_ub, XFN, XC);

    // --- stage 2 (group attention on 8832 unique rows) ---
    k_layernorm<<<MG, 128, 0, stream>>>(XC, XNB, ln3_g, ln3_b, 1);
    mf_gemm<<<dim3(9, 69), 256, 0, stream>>>(XNB, qkv1_w, (const float*)nullptr, (const float*)nullptr, BIG1, MG, 1152, 384, 0);
    k_attn2<<<NGRP, 256, 0, stream>>>(BIG1, idx, BIG2);
    mf_gemm<<<dim3(3, 256), 256, 0, stream>>>(BIG2, proj1_w, proj1_b, (const float*)nullptr, ATT, NGRP * 16, 384, 384, 0);
    k_groupmax<<<NGRP, 128, 0, stream>>>(ATT, XC, idx, cidx, bn_g, bn_b, bn_mean, bn_var, VIS);
    k_propagate<<<BB * 128, 128, 0, stream>>>(center1, center2, XC, VIS, XFN);

    // --- final adapter + slice ---
    k_build_xfinal<<<(M1 * DD + 255) / 256, 256, 0, stream>>>(XC, XFN, XFIN);
    k_gemm<<<dim3(1, 139), 256, 0, stream>>>(XFIN, ad1_dw, ad1_db, (const float*)nullptr, T16, M1, 16, 384, 1);
    k_final<<<BB * 129, 128, 0, stream>>>(T16, ad1_uw, ad1_ub, XFIN, out_x);
}

// Round 4
// 591.363 us; speedup vs baseline: 2.0503x; 1.2352x over previous
//
#include <hip/hip_runtime.h>
#include <hip/hip_bf16.h>

typedef __hip_bfloat16 bf16;
typedef __attribute__((ext_vector_type(8))) short short8;
typedef __attribute__((ext_vector_type(4))) float f32x4;

#define DEV static __device__ __forceinline__

DEV float b2f(bf16 v) { return __bfloat162float(v); }
DEV bf16 f2b(float v) { return __float2bfloat16(v); }
DEV unsigned short f2bu(float v) { return __builtin_bit_cast(unsigned short, __float2bfloat16(v)); }
DEV float u2f(unsigned short u) { return __uint_as_float(((unsigned int)u) << 16); }
DEV float gelu(float x) { return 0.5f * x * (1.0f + erff(x * 0.70710678118654752f)); }

// Problem constants
#define BB 64
#define NT 139     // 1 + T + G1
#define DD 384
#define TT 10
#define HH 6
#define GG 138     // G1 + T
#define M1 8896    // BB*NT
#define MG 8832    // BB*GG
#define NGRP 2048  // BB*S
#define SCALE 0.125f

// Workspace byte offsets (proven layout; ws demand 85.7 MB)
#define XC_OFF   0UL          // f32 8896x384 residual stream, live whole call
#define VIS_OFF  13664256UL   // f32 2048x384
#define XNB_OFF  16809984UL   // bf16 8896x384: LN out; attn1 o; dead after consumer
#define XFN_OFF  23642112UL   // f32 8896x384: fc2 out; x_prop
#define T16_OFF  37306368UL   // f32 8896x16
#define BIG1_OFF 37875712UL   // bf16 8896x1152: qkv / qkv1
#define BIG2_OFF 58372096UL   // bf16 8896x1536 fc1h / bf16 32768x384 o1 / f32 x_final
#define ATT_OFF  XNB_OFF      // bf16 32768x384 proj1 out (overlays dead XNB..BIG1 prefix)

#define OUT_X 3170304  // 64*129*384

DEV float4 ld4(const float* p) { return *(const float4*)p; }
DEV float4 ld4(const bf16* p) {
    ushort4 u = *(const ushort4*)p;
    return make_float4(u2f(u.x), u2f(u.y), u2f(u.z), u2f(u.w));
}
DEV void stc(float* p, float v) { *p = v; }
DEV void stc(bf16* p, float v) { *p = f2b(v); }

// ---------- concat: xc = [x[:, :1], prompt, x[:, 1:]] ----------
__global__ __launch_bounds__(256) void k_build_xc(const float* __restrict__ x,
                                                  const float* __restrict__ pe,
                                                  float* __restrict__ xc) {
    int i = blockIdx.x * 256 + threadIdx.x;
    if (i >= M1 * DD) return;
    int d = i % DD, r = i / DD, n = r % NT, b = r / NT;
    float v;
    if (n == 0)        v = x[(b * 129) * DD + d];
    else if (n <= TT)  v = pe[(n - 1) * DD + d];
    else               v = x[(b * 129 + n - TT) * DD + d];
    xc[i] = v;
}

// ---------- layernorm f32 -> bf16 (mode 1: gather row (r/138)*139+1+(r%138)) ----------
__global__ __launch_bounds__(128) void k_layernorm(const float* __restrict__ src, bf16* __restrict__ dst,
                                                   const float* __restrict__ g, const float* __restrict__ bta,
                                                   int mode) {
    int r = blockIdx.x;
    int srow = r;
    if (mode) srow = (r / GG) * NT + 1 + (r % GG);
    const float* p = src + (size_t)srow * DD;
    int t = threadIdx.x;
    float v0 = p[t], v1 = p[t + 128], v2 = p[t + 256];
    __shared__ float red[4];
    float s = v0 + v1 + v2;
    for (int off = 32; off; off >>= 1) s += __shfl_down(s, off, 64);
    if ((t & 63) == 0) red[t >> 6] = s;
    __syncthreads();
    float mean = (red[0] + red[1]) * (1.0f / 384.0f);
    float d0 = v0 - mean, d1 = v1 - mean, d2 = v2 - mean;
    float s2 = d0 * d0 + d1 * d1 + d2 * d2;
    for (int off = 32; off; off >>= 1) s2 += __shfl_down(s2, off, 64);
    if ((t & 63) == 0) red[2 + (t >> 6)] = s2;
    __syncthreads();
    float rstd = rsqrtf((red[2] + red[3]) * (1.0f / 384.0f) + 1e-5f);
    bf16* q = dst + (size_t)r * DD;
    q[t]       = f2b(d0 * rstd * g[t]       + bta[t]);
    q[t + 128] = f2b(d1 * rstd * g[t + 128] + bta[t + 128]);
    q[t + 256] = f2b(d2 * rstd * g[t + 256] + bta[t + 256]);
}

// ---------- MFMA GEMM: C[M,N] = act(A[M,K]bf16 @ W[N,K]^T f32 + bias) (+res) ----------
template <typename TC>
__global__ __launch_bounds__(256) void mf_gemm(const bf16* __restrict__ A, const float* __restrict__ W,
                                               const float* __restrict__ bias, const float* __restrict__ res,
                                               TC* __restrict__ C, int M, int N, int K, int act) {
    __shared__ bf16 As[128][40];
    __shared__ bf16 Ws[128][40];
    int t = threadIdx.x;
    int m0 = blockIdx.y * 128, n0 = blockIdx.x * 128;
    int lane = t & 63, wv = t >> 6;
    int wm = (wv >> 1) * 64, wn = (wv & 1) * 64;
    int fr = lane & 15, fq = lane >> 4;
    int ar = t >> 2, ac = (t & 3) * 8;
    int wr = t >> 3, wc = (t & 7) * 4;
    f32x4 acc[4][4] = {};
    for (int k0 = 0; k0 < K; k0 += 32) {
#pragma unroll
        for (int p = 0; p < 2; ++p) {
            int row = p * 64 + ar;
            int gr = m0 + row; if (gr >= M) gr = M - 1;
            *(uint4*)&As[row][ac] = *(const uint4*)(A + (size_t)gr * K + k0 + ac);
        }
#pragma unroll
        for (int p = 0; p < 4; ++p) {
            int row = p * 32 + wr;
            float4 wvv = *(const float4*)(W + (size_t)(n0 + row) * K + k0 + wc);
            Ws[row][wc + 0] = f2b(wvv.x); Ws[row][wc + 1] = f2b(wvv.y);
            Ws[row][wc + 2] = f2b(wvv.z); Ws[row][wc + 3] = f2b(wvv.w);
        }
        __syncthreads();
        short8 af[4], bfr[4];
#pragma unroll
        for (int i = 0; i < 4; ++i) af[i] = *(const short8*)&As[wm + i * 16 + fr][fq * 8];
#pragma unroll
        for (int j = 0; j < 4; ++j) bfr[j] = *(const short8*)&Ws[wn + j * 16 + fr][fq * 8];
#pragma unroll
        for (int i = 0; i < 4; ++i)
#pragma unroll
            for (int j = 0; j < 4; ++j)
                acc[i][j] = __builtin_amdgcn_mfma_f32_16x16x32_bf16(af[i], bfr[j], acc[i][j], 0, 0, 0);
        __syncthreads();
    }
#pragma unroll
    for (int i = 0; i < 4; ++i) {
#pragma unroll
        for (int r = 0; r < 4; ++r) {
            int row = m0 + wm + i * 16 + fq * 4 + r;
            if (row < M) {
                size_t ro = (size_t)row * N;
#pragma unroll
                for (int j = 0; j < 4; ++j) {
                    int col = n0 + wn + j * 16 + fr;
                    float c = acc[i][j][r];
                    if (bias) c += bias[col];
                    if (act == 1) c = gelu(c);
                    if (res) c += res[ro + col];
                    stc(&C[ro + col], c);
                }
            }
        }
    }
}

// ---------- small fp32 GEMM (N=16 adapters) ----------
#define BM 64
#define BN 64
#define BKK 16
template <typename TA, typename TC>
__global__ __launch_bounds__(256) void k_gemm(const TA* __restrict__ A, const float* __restrict__ W,
                                              const float* __restrict__ bias, const float* __restrict__ res,
                                              TC* __restrict__ C, int M, int N, int K, int act) {
    __shared__ float As[BKK][BM + 4];
    __shared__ float Wsm[BKK][BN + 4];
    int t = threadIdx.x;
    int tx = t & 15, ty = t >> 4;
    int m0 = blockIdx.y * BM, n0 = blockIdx.x * BN;
    int lr = t >> 2;
    int lk = (t & 3) * 4;
    float acc[4][4] = {};
    for (int k0 = 0; k0 < K; k0 += BKK) {
        float4 av = ld4(A + (size_t)(m0 + lr) * K + k0 + lk);
        As[lk + 0][lr] = av.x; As[lk + 1][lr] = av.y;
        As[lk + 2][lr] = av.z; As[lk + 3][lr] = av.w;
        int wrr = n0 + lr;
        float4 wv = make_float4(0.f, 0.f, 0.f, 0.f);
        if (wrr < N) wv = ld4(W + (size_t)wrr * K + k0 + lk);
        Wsm[lk + 0][lr] = wv.x; Wsm[lk + 1][lr] = wv.y;
        Wsm[lk + 2][lr] = wv.z; Wsm[lk + 3][lr] = wv.w;
        __syncthreads();
#pragma unroll
        for (int k = 0; k < BKK; ++k) {
            float a0 = As[k][ty * 4 + 0], a1 = As[k][ty * 4 + 1];
            float a2 = As[k][ty * 4 + 2], a3 = As[k][ty * 4 + 3];
            float b0 = Wsm[k][tx * 4 + 0], b1 = Wsm[k][tx * 4 + 1];
            float b2 = Wsm[k][tx * 4 + 2], b3 = Wsm[k][tx * 4 + 3];
            acc[0][0] += a0 * b0; acc[0][1] += a0 * b1; acc[0][2] += a0 * b2; acc[0][3] += a0 * b3;
            acc[1][0] += a1 * b0; acc[1][1] += a1 * b1; acc[1][2] += a1 * b2; acc[1][3] += a1 * b3;
            acc[2][0] += a2 * b0; acc[2][1] += a2 * b1; acc[2][2] += a2 * b2; acc[2][3] += a2 * b3;
            acc[3][0] += a3 * b0; acc[3][1] += a3 * b1; acc[3][2] += a3 * b2; acc[3][3] += a3 * b3;
        }
        __syncthreads();
    }
#pragma unroll
    for (int i = 0; i < 4; ++i) {
        int m = m0 + ty * 4 + i;
        size_t ro = (size_t)m * N;
#pragma unroll
        for (int j = 0; j < 4; ++j) {
            int n = n0 + tx * 4 + j;
            if (n < N) {
                float c = acc[i][j];
                if (bias) c += bias[n];
                if (act == 1) c = gelu(c);
                if (res) c += res[ro + n];
                stc(&C[ro + n], c);
            }
        }
    }
}

// ---------- stage-1 attention (MFMA): one block per (b,h) ----------
// S = Q@K^T (139x139, k=64), softmax rows, attn->f32 out, O = P@V -> bf16 o.
__global__ __launch_bounds__(256) void k_attn1(const bf16* __restrict__ qkv, bf16* __restrict__ o_out,
                                               float* __restrict__ attn_out) {
    int bh = blockIdx.x;
    int b = bh / HH, h = bh % HH;
    __shared__ unsigned short Kl[144][72];   // K rows, padded to 144, stride 72 (16B-aligned)
    __shared__ unsigned short Vt[64][160];   // V^T: [d][m], m padded to 160
    __shared__ unsigned short Pl[4][16][160];// per-wave P tile
    int t = threadIdx.x;
    int lane = t & 63, wv = t >> 6;
    int fr = lane & 15, fq = lane >> 4;
    const unsigned short* q16 = (const unsigned short*)qkv;
    size_t base = (size_t)b * NT * 1152;

    // zero Vt (10240) and Pl (10240)
    uint4 z4 = make_uint4(0, 0, 0, 0);
    for (int i = t * 8; i < 64 * 160; i += 2048) *(uint4*)(&Vt[0][0] + i) = z4;
    for (int i = t * 8; i < 4 * 16 * 160; i += 2048) *(uint4*)(&Pl[0][0][0] + i) = z4;
    // stage K (b128), zero-pad rows 139..143
    for (int i = t; i < 144 * 8; i += 256) {
        int row = i >> 3, ch = (i & 7) * 8;
        uint4 v = z4;
        if (row < NT) v = *(const uint4*)(q16 + base + row * 1152 + 384 + h * 64 + ch);
        *(uint4*)&Kl[row][ch] = v;
    }
    // stage V^T (scalar transpose)
    for (int i = t; i < NT * 16; i += 256) {
        int m = i >> 4, dq = (i & 15) * 4;
        ushort4 v = *(const ushort4*)(q16 + base + m * 1152 + 768 + h * 64 + dq);
        Vt[dq + 0][m] = v.x; Vt[dq + 1][m] = v.y;
        Vt[dq + 2][m] = v.z; Vt[dq + 3][m] = v.w;
    }
    __syncthreads();

    for (int nt = wv; nt < 9; nt += 4) {
        int n0 = nt * 16;
        int arow = n0 + fr; if (arow > NT - 1) arow = NT - 1;
        const unsigned short* qp = q16 + base + (size_t)arow * 1152 + h * 64 + fq * 8;
        short8 a0 = *(const short8*)qp;
        short8 a1 = *(const short8*)(qp + 32);
        f32x4 s[9] = {};
#pragma unroll
        for (int mt = 0; mt < 9; ++mt) {
            short8 b0 = *(const short8*)&Kl[mt * 16 + fr][fq * 8];
            short8 b1 = *(const short8*)&Kl[mt * 16 + fr][32 + fq * 8];
            s[mt] = __builtin_amdgcn_mfma_f32_16x16x32_bf16(a0, b0, s[mt], 0, 0, 0);
            s[mt] = __builtin_amdgcn_mfma_f32_16x16x32_bf16(a1, b1, s[mt], 0, 0, 0);
        }
#pragma unroll
        for (int r = 0; r < 4; ++r) {
            float e[9];
            float mx = -1e30f;
#pragma unroll
            for (int mt = 0; mt < 9; ++mt) {
                int col = mt * 16 + fr;
                float v = (col < NT) ? s[mt][r] * SCALE : -1e30f;
                e[mt] = v;
                mx = fmaxf(mx, v);
            }
#pragma unroll
            for (int off = 1; off < 16; off <<= 1) mx = fmaxf(mx, __shfl_xor(mx, off, 64));
            float sm = 0.f;
#pragma unroll
            for (int mt = 0; mt < 9; ++mt) { e[mt] = __expf(e[mt] - mx); sm += e[mt]; }
#pragma unroll
            for (int off = 1; off < 16; off <<= 1) sm += __shfl_xor(sm, off, 64);
            float inv = 1.0f / sm;
            int n = n0 + fq * 4 + r;
            bool nv = n < NT;
            size_t ab = ((size_t)(b * HH + h) * NT + n) * NT;
#pragma unroll
            for (int mt = 0; mt < 9; ++mt) {
                float p = e[mt] * inv;
                int col = mt * 16 + fr;
                if (nv && col < NT) attn_out[ab + col] = p;
                Pl[wv][fq * 4 + r][col] = f2bu(p);
            }
        }
        __syncthreads();  // wave-local: ensures P writes land before frag reads
        f32x4 oac[4] = {};
#pragma unroll
        for (int ks = 0; ks < 5; ++ks) {
            short8 ap = *(const short8*)&Pl[wv][fr][ks * 32 + fq * 8];
#pragma unroll
            for (int dt = 0; dt < 4; ++dt) {
                short8 bv = *(const short8*)&Vt[dt * 16 + fr][ks * 32 + fq * 8];
                oac[dt] = __builtin_amdgcn_mfma_f32_16x16x32_bf16(ap, bv, oac[dt], 0, 0, 0);
            }
        }
#pragma unroll
        for (int dt = 0; dt < 4; ++dt)
#pragma unroll
            for (int r = 0; r < 4; ++r) {
                int n = n0 + fq * 4 + r;
                if (n < NT)
                    o_out[((size_t)(b * NT + n)) * DD + h * 64 + dt * 16 + fr] = f2b(oac[dt][r]);
            }
    }
}

// ---------- stage-2 per-group attention (MFMA): one wave per group ----------
__global__ __launch_bounds__(64) void k_attn2(const bf16* __restrict__ qkv, const int* __restrict__ idx,
                                              bf16* __restrict__ o1) {
    int g = blockIdx.x;
    __shared__ unsigned short Vt2[64][40];  // V^T [d][m], m padded to 32 (stride 40)
    __shared__ unsigned short P2[16][40];   // P [n][m], m padded to 32
    __shared__ int ridx[16];
    int t = threadIdx.x;
    int fr = t & 15, fq = t >> 4;
    const unsigned short* q16 = (const unsigned short*)qkv;
    if (t < 16) ridx[t] = idx[g * 16 + t];
    uint4 z4 = make_uint4(0, 0, 0, 0);
    for (int i = t * 8; i < 64 * 40; i += 512) *(uint4*)(&Vt2[0][0] + i) = z4;
    for (int i = t * 8; i < 16 * 40; i += 512) *(uint4*)(&P2[0][0] + i) = z4;
    __syncthreads();
    size_t qb = (size_t)ridx[fr] * 1152;
    for (int h = 0; h < HH; ++h) {
        // stage V^T for this head
        for (int i = t; i < 256; i += 64) {
            int m = i >> 4, dq = (i & 15) * 4;
            ushort4 v = *(const ushort4*)(q16 + (size_t)ridx[m] * 1152 + 768 + h * 64 + dq);
            Vt2[dq + 0][m] = v.x; Vt2[dq + 1][m] = v.y;
            Vt2[dq + 2][m] = v.z; Vt2[dq + 3][m] = v.w;
        }
        __syncthreads();
        const unsigned short* qp = q16 + qb + h * 64 + fq * 8;
        const unsigned short* kp = q16 + qb + 384 + h * 64 + fq * 8;
        short8 a0 = *(const short8*)qp;
        short8 a1 = *(const short8*)(qp + 32);
        short8 b0 = *(const short8*)kp;
        short8 b1 = *(const short8*)(kp + 32);
        f32x4 s = {};
        s = __builtin_amdgcn_mfma_f32_16x16x32_bf16(a0, b0, s, 0, 0, 0);
        s = __builtin_amdgcn_mfma_f32_16x16x32_bf16(a1, b1, s, 0, 0, 0);
#pragma unroll
        for (int r = 0; r < 4; ++r) {
            float v = s[r] * SCALE;
            float mx = v;
#pragma unroll
            for (int off = 1; off < 16; off <<= 1) mx = fmaxf(mx, __shfl_xor(mx, off, 64));
            float e = __expf(v - mx), sm = e;
#pragma unroll
            for (int off = 1; off < 16; off <<= 1) sm += __shfl_xor(sm, off, 64);
            P2[fq * 4 + r][fr] = f2bu(e / sm);
        }
        __syncthreads();
        short8 ap = *(const short8*)&P2[fr][fq * 8];
        f32x4 oac[4] = {};
#pragma unroll
        for (int dt = 0; dt < 4; ++dt) {
            short8 bv = *(const short8*)&Vt2[dt * 16 + fr][fq * 8];
            oac[dt] = __builtin_amdgcn_mfma_f32_16x16x32_bf16(ap, bv, oac[dt], 0, 0, 0);
        }
#pragma unroll
        for (int dt = 0; dt < 4; ++dt)
#pragma unroll
            for (int r = 0; r < 4; ++r)
                o1[((size_t)(g * 16 + fq * 4 + r)) * DD + h * 64 + dt * 16 + fr] = f2b(oac[dt][r]);
        __syncthreads();
    }
}

// ---------- adapter combine: xc += 0.7*(t16 @ up^T + up_b) + xfn ----------
__global__ __launch_bounds__(128) void k_ad_combine(const float* __restrict__ t16, const float* __restrict__ upw,
                                                    const float* __restrict__ upb, const float* __restrict__ xfn,
                                                    float* xc) {
    int r = blockIdx.x, t = threadIdx.x;
    __shared__ float tl[16];
    if (t < 16) tl[t] = t16[r * 16 + t];
    __syncthreads();
    for (int d = t; d < DD; d += 128) {
        float acc = 0.f;
#pragma unroll
        for (int c = 0; c < 4; ++c) {
            float4 u = *(const float4*)(upw + d * 16 + c * 4);
            acc += tl[c * 4 + 0] * u.x + tl[c * 4 + 1] * u.y
                 + tl[c * 4 + 2] * u.z + tl[c * 4 + 3] * u.w;
        }
        acc += upb[d];
        size_t i = (size_t)r * DD + d;
        xc[i] += 0.7f * acc + xfn[i];
    }
}

// ---------- group residual + max + BN + GELU + centers -> vis ----------
__global__ __launch_bounds__(128) void k_groupmax(const bf16* __restrict__ att, const float* __restrict__ xc,
                                                  const int* __restrict__ idx, const int* __restrict__ cidx,
                                                  const float* __restrict__ bg, const float* __restrict__ bb,
                                                  const float* __restrict__ bmean, const float* __restrict__ bvar,
                                                  float* __restrict__ vis) {
    int g = blockIdx.x, t = threadIdx.x;
    __shared__ int rows[16];
    __shared__ int crow;
    if (t < 16) { int r = idx[g * 16 + t]; rows[t] = (r / GG) * NT + 1 + (r % GG); }
    if (t == 16) { int r = cidx[g]; crow = (r / GG) * NT + 1 + (r % GG); }
    __syncthreads();
    for (int d = t; d < DD; d += 128) {
        float m = -INFINITY;
#pragma unroll
        for (int j = 0; j < 16; ++j) {
            float v = b2f(att[((size_t)(g * 16 + j)) * DD + d]) + xc[(size_t)rows[j] * DD + d];
            m = fmaxf(m, v);
        }
        float bn = (m - bmean[d]) * rsqrtf(bvar[d] + 1e-5f) * bg[d] + bb[d];
        bn = gelu(bn);
        vis[(size_t)g * DD + d] = bn + 0.3f * xc[(size_t)crow * DD + d];
    }
}

// ---------- propagate ----------
__global__ __launch_bounds__(128) void k_propagate(const float* __restrict__ c1, const float* __restrict__ c2,
                                                   const float* __restrict__ xc, const float* __restrict__ vis,
                                                   float* __restrict__ xp) {
    int blk = blockIdx.x;
    int b = blk >> 7, i = blk & 127;
    int t = threadIdx.x;
    __shared__ float wl[32];
    __shared__ float wsum;
    if (t < 32) {
        float dx = c1[(b * 128 + i) * 3 + 0] - c2[(b * 32 + t) * 3 + 0];
        float dy = c1[(b * 128 + i) * 3 + 1] - c2[(b * 32 + t) * 3 + 1];
        float dz = c1[(b * 128 + i) * 3 + 2] - c2[(b * 32 + t) * 3 + 2];
        wl[t] = 1.0f / (dx * dx + dy * dy + dz * dz + 1e-8f);
    }
    __syncthreads();
    if (t == 0) {
        float s = 0.f;
        for (int j = 0; j < 32; ++j) s += wl[j];
        wsum = s;
    }
    __syncthreads();
    float sc = 0.3f / wsum;
    for (int d = t; d < DD; d += 128) {
        float acc = 0.f;
#pragma unroll 8
        for (int j = 0; j < 32; ++j) acc += wl[j] * vis[((size_t)(b * 32 + j)) * DD + d];
        xp[((size_t)(b * 128 + i)) * DD + d] = xc[((size_t)(b * NT + 11 + i)) * DD + d] + sc * acc;
    }
}

// ---------- build x_final = [cls, prompt, x_prop] ----------
__global__ __launch_bounds__(256) void k_build_xfinal(const float* __restrict__ xc, const float* __restrict__ xp,
                                                      float* __restrict__ xf) {
    int i = blockIdx.x * 256 + threadIdx.x;
    if (i >= M1 * DD) return;
    int d = i % DD, r = i / DD, n = r % NT, b = r / NT;
    xf[i] = (n < 11) ? xc[i] : xp[((size_t)(b * 128 + n - 11)) * DD + d];
}

// ---------- final adapter-up + residual + slice -> f32 out ----------
__global__ __launch_bounds__(128) void k_final(const float* __restrict__ t16, const float* __restrict__ upw,
                                               const float* __restrict__ upb, const float* __restrict__ xf,
                                               float* __restrict__ outx) {
    int rb = blockIdx.x, t = threadIdx.x;
    int b = rb / 129, no = rb % 129;
    int src = b * NT + (no == 0 ? 0 : no + TT);
    __shared__ float tl[16];
    if (t < 16) tl[t] = t16[src * 16 + t];
    __syncthreads();
    for (int d = t; d < DD; d += 128) {
        float acc = 0.f;
#pragma unroll
        for (int c = 0; c < 4; ++c) {
            float4 u = *(const float4*)(upw + d * 16 + c * 4);
            acc += tl[c * 4 + 0] * u.x + tl[c * 4 + 1] * u.y
                 + tl[c * 4 + 2] * u.z + tl[c * 4 + 3] * u.w;
        }
        acc += upb[d];
        outx[(size_t)rb * DD + d] = acc + xf[(size_t)src * DD + d];
    }
}

extern "C" void kernel_launch(void* const* d_in, const int* in_sizes, int n_in,
                              void* d_out, int out_size, void* d_ws, size_t ws_size,
                              hipStream_t stream) {
    const float* x_in    = (const float*)d_in[0];
    const float* center1 = (const float*)d_in[2];
    const float* center2 = (const float*)d_in[3];
    const int*   idx     = (const int*)d_in[5];
    const int*   cidx    = (const int*)d_in[6];
    const float* ln1_g   = (const float*)d_in[9];
    const float* ln1_b   = (const float*)d_in[10];
    const float* ln2_g   = (const float*)d_in[11];
    const float* ln2_b   = (const float*)d_in[12];
    const float* qkv_w   = (const float*)d_in[13];
    const float* proj_w  = (const float*)d_in[14];
    const float* proj_b  = (const float*)d_in[15];
    const float* fc1_w   = (const float*)d_in[16];
    const float* fc1_b   = (const float*)d_in[17];
    const float* fc2_w   = (const float*)d_in[18];
    const float* fc2_b   = (const float*)d_in[19];
    const float* ad_dw   = (const float*)d_in[20];
    const float* ad_db   = (const float*)d_in[21];
    const float* ad_uw   = (const float*)d_in[22];
    const float* ad_ub   = (const float*)d_in[23];
    const float* ad1_dw  = (const float*)d_in[24];
    const float* ad1_db  = (const float*)d_in[25];
    const float* ad1_uw  = (const float*)d_in[26];
    const float* ad1_ub  = (const float*)d_in[27];
    const float* prompt  = (const float*)d_in[28];
    const float* bn_g    = (const float*)d_in[29];
    const float* bn_b    = (const float*)d_in[30];
    const float* bn_mean = (const float*)d_in[31];
    const float* bn_var  = (const float*)d_in[32];
    const float* qkv1_w  = (const float*)d_in[33];
    const float* proj1_w = (const float*)d_in[34];
    const float* proj1_b = (const float*)d_in[35];
    const float* ln3_g   = (const float*)d_in[36];
    const float* ln3_b   = (const float*)d_in[37];

    char* wsb = (char*)d_ws;
    float* XC   = (float*)(wsb + XC_OFF);
    float* VIS  = (float*)(wsb + VIS_OFF);
    bf16*  XNB  = (bf16*)(wsb + XNB_OFF);
    float* XFN  = (float*)(wsb + XFN_OFF);
    float* T16  = (float*)(wsb + T16_OFF);
    bf16*  BIG1 = (bf16*)(wsb + BIG1_OFF);
    bf16*  BIG2 = (bf16*)(wsb + BIG2_OFF);
    float* XFIN = (float*)(wsb + BIG2_OFF);
    bf16*  ATT  = (bf16*)(wsb + ATT_OFF);

    float* out_x    = (float*)d_out;
    float* out_attn = out_x + OUT_X;

    // --- stage 1 ---
    k_build_xc<<<(M1 * DD + 255) / 256, 256, 0, stream>>>(x_in, prompt, XC);
    k_layernorm<<<M1, 128, 0, stream>>>(XC, XNB, ln1_g, ln1_b, 0);
    mf_gemm<<<dim3(9, 70), 256, 0, stream>>>(XNB, qkv_w, (const float*)nullptr, (const float*)nullptr, BIG1, M1, 1152, 384, 0);
    k_attn1<<<BB * HH, 256, 0, stream>>>(BIG1, XNB, out_attn);
    mf_gemm<<<dim3(3, 70), 256, 0, stream>>>(XNB, proj_w, proj_b, XC, XC, M1, 384, 384, 0);
    k_layernorm<<<M1, 128, 0, stream>>>(XC, XNB, ln2_g, ln2_b, 0);
    mf_gemm<<<dim3(12, 70), 256, 0, stream>>>(XNB, fc1_w, fc1_b, (const float*)nullptr, BIG2, M1, 1536, 384, 1);
    mf_gemm<<<dim3(3, 70), 256, 0, stream>>>(BIG2, fc2_w, fc2_b, (const float*)nullptr, XFN, M1, 384, 1536, 0);
    k_gemm<<<dim3(1, 139), 256, 0, stream>>>(XFN, ad_dw, ad_db, (const float*)nullptr, T16, M1, 16, 384, 1);
    k_ad_combine<<<M1, 128, 0, stream>>>(T16, ad_uw, ad_ub, XFN, XC);

    // --- stage 2 (group attention on 8832 unique rows) ---
    k_layernorm<<<MG, 128, 0, stream>>>(XC, XNB, ln3_g, ln3_b, 1);
    mf_gemm<<<dim3(9, 69), 256, 0, stream>>>(XNB, qkv1_w, (const float*)nullptr, (const float*)nullptr, BIG1, MG, 1152, 384, 0);
    k_attn2<<<NGRP, 64, 0, stream>>>(BIG1, idx, BIG2);
    mf_gemm<<<dim3(3, 256), 256, 0, stream>>>(BIG2, proj1_w, proj1_b, (const float*)nullptr, ATT, NGRP * 16, 384, 384, 0);
    k_groupmax<<<NGRP, 128, 0, stream>>>(ATT, XC, idx, cidx, bn_g, bn_b, bn_mean, bn_var, VIS);
    k_propagate<<<BB * 128, 128, 0, stream>>>(center1, center2, XC, VIS, XFN);

    // --- final adapter + slice ---
    k_build_xfinal<<<(M1 * DD + 255) / 256, 256, 0, stream>>>(XC, XFN, XFIN);
    k_gemm<<<dim3(1, 139), 256, 0, stream>>>(XFIN, ad1_dw, ad1_db, (const float*)nullptr, T16, M1, 16, 384, 1);
    k_final<<<BB * 129, 128, 0, stream>>>(T16, ad1_uw, ad1_ub, XFIN, out_x);
}

// Round 5
// 541.824 us; speedup vs baseline: 2.2378x; 1.0914x over previous
//
#include <hip/hip_runtime.h>
#include <hip/hip_bf16.h>

typedef __hip_bfloat16 bf16;
typedef __attribute__((ext_vector_type(8))) short short8;
typedef __attribute__((ext_vector_type(4))) float f32x4;

#define DEV static __device__ __forceinline__

DEV float b2f(bf16 v) { return __bfloat162float(v); }
DEV bf16 f2b(float v) { return __float2bfloat16(v); }
DEV unsigned short f2bu(float v) { return __builtin_bit_cast(unsigned short, __float2bfloat16(v)); }
DEV float u2f(unsigned short u) { return __uint_as_float(((unsigned int)u) << 16); }
DEV float gelu(float x) { return 0.5f * x * (1.0f + erff(x * 0.70710678118654752f)); }

// Problem constants
#define BB 64
#define NT 139     // 1 + T + G1
#define DD 384
#define TT 10
#define HH 6
#define GG 138     // G1 + T
#define M1 8896    // BB*NT
#define MG 8832    // BB*GG
#define NGRP 2048  // BB*S
#define SCALE 0.125f

// Workspace byte offsets (proven layout; now + bf16 weights block = 90.4 MB)
#define XC_OFF   0UL          // f32 8896x384 residual stream, live whole call
#define VIS_OFF  13664256UL   // f32 2048x384
#define XNB_OFF  16809984UL   // bf16 8896x384: LN out; attn1 o; dead after consumer
#define XFN_OFF  23642112UL   // f32 8896x384: fc2 out; x_prop
#define T16_OFF  37306368UL   // f32 8896x16
#define BIG1_OFF 37875712UL   // bf16 8896x1152: qkv / qkv1
#define BIG2_OFF 58372096UL   // bf16 8896x1536 fc1h / bf16 32768x384 o1 / f32 x_final
#define ATT_OFF  XNB_OFF      // bf16 32768x384 proj1 out (overlays dead XNB..BIG1 prefix)
#define WB_OFF   85700608UL   // bf16 2359296: pre-converted weights

// bf16 weight block element offsets
#define WB_QKV   0
#define WB_PROJ  442368
#define WB_FC1   589824
#define WB_FC2   1179648
#define WB_QKV1  1769472
#define WB_PROJ1 2211840
#define WB_TOTAL 2359296

#define OUT_X 3170304  // 64*129*384

DEV float4 ld4(const float* p) { return *(const float4*)p; }
DEV float4 ld4(const bf16* p) {
    ushort4 u = *(const ushort4*)p;
    return make_float4(u2f(u.x), u2f(u.y), u2f(u.z), u2f(u.w));
}
DEV void stc(float* p, float v) { *p = v; }
DEV void stc(bf16* p, float v) { *p = f2b(v); }

// ---------- weights f32 -> bf16 (once per call) ----------
__global__ __launch_bounds__(256) void k_wconv(const float* __restrict__ w0, const float* __restrict__ w1,
                                               const float* __restrict__ w2, const float* __restrict__ w3,
                                               const float* __restrict__ w4, const float* __restrict__ w5,
                                               bf16* __restrict__ dst) {
    int i4 = (blockIdx.x * 256 + threadIdx.x) * 4;
    if (i4 >= WB_TOTAL) return;
    const float* s; int off;
    if (i4 < WB_PROJ)       { s = w0; off = WB_QKV; }
    else if (i4 < WB_FC1)   { s = w1; off = WB_PROJ; }
    else if (i4 < WB_FC2)   { s = w2; off = WB_FC1; }
    else if (i4 < WB_QKV1)  { s = w3; off = WB_FC2; }
    else if (i4 < WB_PROJ1) { s = w4; off = WB_QKV1; }
    else                    { s = w5; off = WB_PROJ1; }
    float4 v = *(const float4*)(s + (i4 - off));
    ushort4 u;
    u.x = f2bu(v.x); u.y = f2bu(v.y); u.z = f2bu(v.z); u.w = f2bu(v.w);
    *(ushort4*)((unsigned short*)dst + i4) = u;
}

// ---------- concat: xc = [x[:, :1], prompt, x[:, 1:]] ----------
__global__ __launch_bounds__(256) void k_build_xc(const float* __restrict__ x,
                                                  const float* __restrict__ pe,
                                                  float* __restrict__ xc) {
    int i = blockIdx.x * 256 + threadIdx.x;
    if (i >= M1 * DD) return;
    int d = i % DD, r = i / DD, n = r % NT, b = r / NT;
    float v;
    if (n == 0)        v = x[(b * 129) * DD + d];
    else if (n <= TT)  v = pe[(n - 1) * DD + d];
    else               v = x[(b * 129 + n - TT) * DD + d];
    xc[i] = v;
}

// ---------- layernorm f32 -> bf16 (mode 1: gather row (r/138)*139+1+(r%138)) ----------
__global__ __launch_bounds__(128) void k_layernorm(const float* __restrict__ src, bf16* __restrict__ dst,
                                                   const float* __restrict__ g, const float* __restrict__ bta,
                                                   int mode) {
    int r = blockIdx.x;
    int srow = r;
    if (mode) srow = (r / GG) * NT + 1 + (r % GG);
    const float* p = src + (size_t)srow * DD;
    int t = threadIdx.x;
    float v0 = p[t], v1 = p[t + 128], v2 = p[t + 256];
    __shared__ float red[4];
    float s = v0 + v1 + v2;
    for (int off = 32; off; off >>= 1) s += __shfl_down(s, off, 64);
    if ((t & 63) == 0) red[t >> 6] = s;
    __syncthreads();
    float mean = (red[0] + red[1]) * (1.0f / 384.0f);
    float d0 = v0 - mean, d1 = v1 - mean, d2 = v2 - mean;
    float s2 = d0 * d0 + d1 * d1 + d2 * d2;
    for (int off = 32; off; off >>= 1) s2 += __shfl_down(s2, off, 64);
    if ((t & 63) == 0) red[2 + (t >> 6)] = s2;
    __syncthreads();
    float rstd = rsqrtf((red[2] + red[3]) * (1.0f / 384.0f) + 1e-5f);
    bf16* q = dst + (size_t)r * DD;
    q[t]       = f2b(d0 * rstd * g[t]       + bta[t]);
    q[t + 128] = f2b(d1 * rstd * g[t + 128] + bta[t + 128]);
    q[t + 256] = f2b(d2 * rstd * g[t + 256] + bta[t + 256]);
}

// ---------- MFMA GEMM: C[M,N] = act(A[M,K]bf16 @ W[N,K]^T bf16 + bias) (+res) ----------
// 128x64 block tile, 4 waves (2x2) each 64x32 via 4x2 of 16x16x32 MFMAs, BK=32.
// N multiple of 64, K multiple of 32; M guarded (clamped loads, guarded stores).
template <typename TC>
__global__ __launch_bounds__(256) void mf_gemm(const bf16* __restrict__ A, const bf16* __restrict__ W,
                                               const float* __restrict__ bias, const float* __restrict__ res,
                                               TC* __restrict__ C, int M, int N, int K, int act) {
    __shared__ bf16 As[128][40];
    __shared__ bf16 Ws[64][40];
    int t = threadIdx.x;
    int m0 = blockIdx.y * 128, n0 = blockIdx.x * 64;
    int lane = t & 63, wv = t >> 6;
    int wm = (wv >> 1) * 64, wn = (wv & 1) * 32;
    int fr = lane & 15, fq = lane >> 4;
    int sr = t >> 2, sc = (t & 3) * 8;   // staging: 4 thr/row, 8 bf16 (16B) each
    f32x4 acc[4][2] = {};
    for (int k0 = 0; k0 < K; k0 += 32) {
        int gr = m0 + sr; if (gr >= M) gr = M - 1;
        *(uint4*)&As[sr][sc] = *(const uint4*)(A + (size_t)gr * K + k0 + sc);
        int gr2 = m0 + 64 + sr; if (gr2 >= M) gr2 = M - 1;
        *(uint4*)&As[64 + sr][sc] = *(const uint4*)(A + (size_t)gr2 * K + k0 + sc);
        *(uint4*)&Ws[sr][sc] = *(const uint4*)(W + (size_t)(n0 + sr) * K + k0 + sc);
        __syncthreads();
        short8 af[4], bfr[2];
#pragma unroll
        for (int i = 0; i < 4; ++i) af[i] = *(const short8*)&As[wm + i * 16 + fr][fq * 8];
#pragma unroll
        for (int j = 0; j < 2; ++j) bfr[j] = *(const short8*)&Ws[wn + j * 16 + fr][fq * 8];
#pragma unroll
        for (int i = 0; i < 4; ++i)
#pragma unroll
            for (int j = 0; j < 2; ++j)
                acc[i][j] = __builtin_amdgcn_mfma_f32_16x16x32_bf16(af[i], bfr[j], acc[i][j], 0, 0, 0);
        __syncthreads();
    }
#pragma unroll
    for (int i = 0; i < 4; ++i) {
#pragma unroll
        for (int r = 0; r < 4; ++r) {
            int row = m0 + wm + i * 16 + fq * 4 + r;
            if (row < M) {
                size_t ro = (size_t)row * N;
#pragma unroll
                for (int j = 0; j < 2; ++j) {
                    int col = n0 + wn + j * 16 + fr;
                    float c = acc[i][j][r];
                    if (bias) c += bias[col];
                    if (act == 1) c = gelu(c);
                    if (res) c += res[ro + col];
                    stc(&C[ro + col], c);
                }
            }
        }
    }
}

// ---------- small fp32 GEMM (N=16 adapters) ----------
#define BM 64
#define BN 64
#define BKK 16
template <typename TA, typename TC>
__global__ __launch_bounds__(256) void k_gemm(const TA* __restrict__ A, const float* __restrict__ W,
                                              const float* __restrict__ bias, const float* __restrict__ res,
                                              TC* __restrict__ C, int M, int N, int K, int act) {
    __shared__ float As[BKK][BM + 4];
    __shared__ float Wsm[BKK][BN + 4];
    int t = threadIdx.x;
    int tx = t & 15, ty = t >> 4;
    int m0 = blockIdx.y * BM, n0 = blockIdx.x * BN;
    int lr = t >> 2;
    int lk = (t & 3) * 4;
    float acc[4][4] = {};
    for (int k0 = 0; k0 < K; k0 += BKK) {
        float4 av = ld4(A + (size_t)(m0 + lr) * K + k0 + lk);
        As[lk + 0][lr] = av.x; As[lk + 1][lr] = av.y;
        As[lk + 2][lr] = av.z; As[lk + 3][lr] = av.w;
        int wrr = n0 + lr;
        float4 wv = make_float4(0.f, 0.f, 0.f, 0.f);
        if (wrr < N) wv = ld4(W + (size_t)wrr * K + k0 + lk);
        Wsm[lk + 0][lr] = wv.x; Wsm[lk + 1][lr] = wv.y;
        Wsm[lk + 2][lr] = wv.z; Wsm[lk + 3][lr] = wv.w;
        __syncthreads();
#pragma unroll
        for (int k = 0; k < BKK; ++k) {
            float a0 = As[k][ty * 4 + 0], a1 = As[k][ty * 4 + 1];
            float a2 = As[k][ty * 4 + 2], a3 = As[k][ty * 4 + 3];
            float b0 = Wsm[k][tx * 4 + 0], b1 = Wsm[k][tx * 4 + 1];
            float b2 = Wsm[k][tx * 4 + 2], b3 = Wsm[k][tx * 4 + 3];
            acc[0][0] += a0 * b0; acc[0][1] += a0 * b1; acc[0][2] += a0 * b2; acc[0][3] += a0 * b3;
            acc[1][0] += a1 * b0; acc[1][1] += a1 * b1; acc[1][2] += a1 * b2; acc[1][3] += a1 * b3;
            acc[2][0] += a2 * b0; acc[2][1] += a2 * b1; acc[2][2] += a2 * b2; acc[2][3] += a2 * b3;
            acc[3][0] += a3 * b0; acc[3][1] += a3 * b1; acc[3][2] += a3 * b2; acc[3][3] += a3 * b3;
        }
        __syncthreads();
    }
#pragma unroll
    for (int i = 0; i < 4; ++i) {
        int m = m0 + ty * 4 + i;
        size_t ro = (size_t)m * N;
#pragma unroll
        for (int j = 0; j < 4; ++j) {
            int n = n0 + tx * 4 + j;
            if (n < N) {
                float c = acc[i][j];
                if (bias) c += bias[n];
                if (act == 1) c = gelu(c);
                if (res) c += res[ro + n];
                stc(&C[ro + n], c);
            }
        }
    }
}

// ---------- stage-1 attention (MFMA): one block per (b,h) ----------
__global__ __launch_bounds__(256) void k_attn1(const bf16* __restrict__ qkv, bf16* __restrict__ o_out,
                                               float* __restrict__ attn_out) {
    int bh = blockIdx.x;
    int b = bh / HH, h = bh % HH;
    __shared__ unsigned short Kl[144][72];
    __shared__ unsigned short Vt[64][160];
    __shared__ unsigned short Pl[4][16][160];
    int t = threadIdx.x;
    int lane = t & 63, wv = t >> 6;
    int fr = lane & 15, fq = lane >> 4;
    const unsigned short* q16 = (const unsigned short*)qkv;
    size_t base = (size_t)b * NT * 1152;

    uint4 z4 = make_uint4(0, 0, 0, 0);
    for (int i = t * 8; i < 64 * 160; i += 2048) *(uint4*)(&Vt[0][0] + i) = z4;
    for (int i = t * 8; i < 4 * 16 * 160; i += 2048) *(uint4*)(&Pl[0][0][0] + i) = z4;
    for (int i = t; i < 144 * 8; i += 256) {
        int row = i >> 3, ch = (i & 7) * 8;
        uint4 v = z4;
        if (row < NT) v = *(const uint4*)(q16 + base + row * 1152 + 384 + h * 64 + ch);
        *(uint4*)&Kl[row][ch] = v;
    }
    for (int i = t; i < NT * 16; i += 256) {
        int m = i >> 4, dq = (i & 15) * 4;
        ushort4 v = *(const ushort4*)(q16 + base + m * 1152 + 768 + h * 64 + dq);
        Vt[dq + 0][m] = v.x; Vt[dq + 1][m] = v.y;
        Vt[dq + 2][m] = v.z; Vt[dq + 3][m] = v.w;
    }
    __syncthreads();

    for (int nt = wv; nt < 9; nt += 4) {
        int n0 = nt * 16;
        int arow = n0 + fr; if (arow > NT - 1) arow = NT - 1;
        const unsigned short* qp = q16 + base + (size_t)arow * 1152 + h * 64 + fq * 8;
        short8 a0 = *(const short8*)qp;
        short8 a1 = *(const short8*)(qp + 32);
        f32x4 s[9] = {};
#pragma unroll
        for (int mt = 0; mt < 9; ++mt) {
            short8 b0 = *(const short8*)&Kl[mt * 16 + fr][fq * 8];
            short8 b1 = *(const short8*)&Kl[mt * 16 + fr][32 + fq * 8];
            s[mt] = __builtin_amdgcn_mfma_f32_16x16x32_bf16(a0, b0, s[mt], 0, 0, 0);
            s[mt] = __builtin_amdgcn_mfma_f32_16x16x32_bf16(a1, b1, s[mt], 0, 0, 0);
        }
#pragma unroll
        for (int r = 0; r < 4; ++r) {
            float e[9];
            float mx = -1e30f;
#pragma unroll
            for (int mt = 0; mt < 9; ++mt) {
                int col = mt * 16 + fr;
                float v = (col < NT) ? s[mt][r] * SCALE : -1e30f;
                e[mt] = v;
                mx = fmaxf(mx, v);
            }
#pragma unroll
            for (int off = 1; off < 16; off <<= 1) mx = fmaxf(mx, __shfl_xor(mx, off, 64));
            float sm = 0.f;
#pragma unroll
            for (int mt = 0; mt < 9; ++mt) { e[mt] = __expf(e[mt] - mx); sm += e[mt]; }
#pragma unroll
            for (int off = 1; off < 16; off <<= 1) sm += __shfl_xor(sm, off, 64);
            float inv = 1.0f / sm;
            int n = n0 + fq * 4 + r;
            bool nv = n < NT;
            size_t ab = ((size_t)(b * HH + h) * NT + n) * NT;
#pragma unroll
            for (int mt = 0; mt < 9; ++mt) {
                float p = e[mt] * inv;
                int col = mt * 16 + fr;
                if (nv && col < NT) attn_out[ab + col] = p;
                Pl[wv][fq * 4 + r][col] = f2bu(p);
            }
        }
        __syncthreads();
        f32x4 oac[4] = {};
#pragma unroll
        for (int ks = 0; ks < 5; ++ks) {
            short8 ap = *(const short8*)&Pl[wv][fr][ks * 32 + fq * 8];
#pragma unroll
            for (int dt = 0; dt < 4; ++dt) {
                short8 bv = *(const short8*)&Vt[dt * 16 + fr][ks * 32 + fq * 8];
                oac[dt] = __builtin_amdgcn_mfma_f32_16x16x32_bf16(ap, bv, oac[dt], 0, 0, 0);
            }
        }
#pragma unroll
        for (int dt = 0; dt < 4; ++dt)
#pragma unroll
            for (int r = 0; r < 4; ++r) {
                int n = n0 + fq * 4 + r;
                if (n < NT)
                    o_out[((size_t)(b * NT + n)) * DD + h * 64 + dt * 16 + fr] = f2b(oac[dt][r]);
            }
    }
}

// ---------- stage-2 per-group attention (MFMA): one wave per group ----------
__global__ __launch_bounds__(64) void k_attn2(const bf16* __restrict__ qkv, const int* __restrict__ idx,
                                              bf16* __restrict__ o1) {
    int g = blockIdx.x;
    __shared__ unsigned short Vt2[64][40];
    __shared__ unsigned short P2[16][40];
    __shared__ int ridx[16];
    int t = threadIdx.x;
    int fr = t & 15, fq = t >> 4;
    const unsigned short* q16 = (const unsigned short*)qkv;
    if (t < 16) ridx[t] = idx[g * 16 + t];
    uint4 z4 = make_uint4(0, 0, 0, 0);
    for (int i = t * 8; i < 64 * 40; i += 512) *(uint4*)(&Vt2[0][0] + i) = z4;
    for (int i = t * 8; i < 16 * 40; i += 512) *(uint4*)(&P2[0][0] + i) = z4;
    __syncthreads();
    size_t qb = (size_t)ridx[fr] * 1152;
    for (int h = 0; h < HH; ++h) {
        for (int i = t; i < 256; i += 64) {
            int m = i >> 4, dq = (i & 15) * 4;
            ushort4 v = *(const ushort4*)(q16 + (size_t)ridx[m] * 1152 + 768 + h * 64 + dq);
            Vt2[dq + 0][m] = v.x; Vt2[dq + 1][m] = v.y;
            Vt2[dq + 2][m] = v.z; Vt2[dq + 3][m] = v.w;
        }
        __syncthreads();
        const unsigned short* qp = q16 + qb + h * 64 + fq * 8;
        const unsigned short* kp = q16 + qb + 384 + h * 64 + fq * 8;
        short8 a0 = *(const short8*)qp;
        short8 a1 = *(const short8*)(qp + 32);
        short8 b0 = *(const short8*)kp;
        short8 b1 = *(const short8*)(kp + 32);
        f32x4 s = {};
        s = __builtin_amdgcn_mfma_f32_16x16x32_bf16(a0, b0, s, 0, 0, 0);
        s = __builtin_amdgcn_mfma_f32_16x16x32_bf16(a1, b1, s, 0, 0, 0);
#pragma unroll
        for (int r = 0; r < 4; ++r) {
            float v = s[r] * SCALE;
            float mx = v;
#pragma unroll
            for (int off = 1; off < 16; off <<= 1) mx = fmaxf(mx, __shfl_xor(mx, off, 64));
            float e = __expf(v - mx), sm = e;
#pragma unroll
            for (int off = 1; off < 16; off <<= 1) sm += __shfl_xor(sm, off, 64);
            P2[fq * 4 + r][fr] = f2bu(e / sm);
        }
        __syncthreads();
        short8 ap = *(const short8*)&P2[fr][fq * 8];
        f32x4 oac[4] = {};
#pragma unroll
        for (int dt = 0; dt < 4; ++dt) {
            short8 bv = *(const short8*)&Vt2[dt * 16 + fr][fq * 8];
            oac[dt] = __builtin_amdgcn_mfma_f32_16x16x32_bf16(ap, bv, oac[dt], 0, 0, 0);
        }
#pragma unroll
        for (int dt = 0; dt < 4; ++dt)
#pragma unroll
            for (int r = 0; r < 4; ++r)
                o1[((size_t)(g * 16 + fq * 4 + r)) * DD + h * 64 + dt * 16 + fr] = f2b(oac[dt][r]);
        __syncthreads();
    }
}

// ---------- adapter combine: xc += 0.7*(t16 @ up^T + up_b) + xfn ----------
__global__ __launch_bounds__(128) void k_ad_combine(const float* __restrict__ t16, const float* __restrict__ upw,
                                                    const float* __restrict__ upb, const float* __restrict__ xfn,
                                                    float* xc) {
    int r = blockIdx.x, t = threadIdx.x;
    __shared__ float tl[16];
    if (t < 16) tl[t] = t16[r * 16 + t];
    __syncthreads();
    for (int d = t; d < DD; d += 128) {
        float acc = 0.f;
#pragma unroll
        for (int c = 0; c < 4; ++c) {
            float4 u = *(const float4*)(upw + d * 16 + c * 4);
            acc += tl[c * 4 + 0] * u.x + tl[c * 4 + 1] * u.y
                 + tl[c * 4 + 2] * u.z + tl[c * 4 + 3] * u.w;
        }
        acc += upb[d];
        size_t i = (size_t)r * DD + d;
        xc[i] += 0.7f * acc + xfn[i];
    }
}

// ---------- group residual + max + BN + GELU + centers -> vis ----------
__global__ __launch_bounds__(128) void k_groupmax(const bf16* __restrict__ att, const float* __restrict__ xc,
                                                  const int* __restrict__ idx, const int* __restrict__ cidx,
                                                  const float* __restrict__ bg, const float* __restrict__ bb,
                                                  const float* __restrict__ bmean, const float* __restrict__ bvar,
                                                  float* __restrict__ vis) {
    int g = blockIdx.x, t = threadIdx.x;
    __shared__ int rows[16];
    __shared__ int crow;
    if (t < 16) { int r = idx[g * 16 + t]; rows[t] = (r / GG) * NT + 1 + (r % GG); }
    if (t == 16) { int r = cidx[g]; crow = (r / GG) * NT + 1 + (r % GG); }
    __syncthreads();
    for (int d = t; d < DD; d += 128) {
        float m = -INFINITY;
#pragma unroll
        for (int j = 0; j < 16; ++j) {
            float v = b2f(att[((size_t)(g * 16 + j)) * DD + d]) + xc[(size_t)rows[j] * DD + d];
            m = fmaxf(m, v);
        }
        float bn = (m - bmean[d]) * rsqrtf(bvar[d] + 1e-5f) * bg[d] + bb[d];
        bn = gelu(bn);
        vis[(size_t)g * DD + d] = bn + 0.3f * xc[(size_t)crow * DD + d];
    }
}

// ---------- propagate ----------
__global__ __launch_bounds__(128) void k_propagate(const float* __restrict__ c1, const float* __restrict__ c2,
                                                   const float* __restrict__ xc, const float* __restrict__ vis,
                                                   float* __restrict__ xp) {
    int blk = blockIdx.x;
    int b = blk >> 7, i = blk & 127;
    int t = threadIdx.x;
    __shared__ float wl[32];
    __shared__ float wsum;
    if (t < 32) {
        float dx = c1[(b * 128 + i) * 3 + 0] - c2[(b * 32 + t) * 3 + 0];
        float dy = c1[(b * 128 + i) * 3 + 1] - c2[(b * 32 + t) * 3 + 1];
        float dz = c1[(b * 128 + i) * 3 + 2] - c2[(b * 32 + t) * 3 + 2];
        wl[t] = 1.0f / (dx * dx + dy * dy + dz * dz + 1e-8f);
    }
    __syncthreads();
    if (t == 0) {
        float s = 0.f;
        for (int j = 0; j < 32; ++j) s += wl[j];
        wsum = s;
    }
    __syncthreads();
    float sc = 0.3f / wsum;
    for (int d = t; d < DD; d += 128) {
        float acc = 0.f;
#pragma unroll 8
        for (int j = 0; j < 32; ++j) acc += wl[j] * vis[((size_t)(b * 32 + j)) * DD + d];
        xp[((size_t)(b * 128 + i)) * DD + d] = xc[((size_t)(b * NT + 11 + i)) * DD + d] + sc * acc;
    }
}

// ---------- build x_final = [cls, prompt, x_prop] ----------
__global__ __launch_bounds__(256) void k_build_xfinal(const float* __restrict__ xc, const float* __restrict__ xp,
                                                      float* __restrict__ xf) {
    int i = blockIdx.x * 256 + threadIdx.x;
    if (i >= M1 * DD) return;
    int d = i % DD, r = i / DD, n = r % NT, b = r / NT;
    xf[i] = (n < 11) ? xc[i] : xp[((size_t)(b * 128 + n - 11)) * DD + d];
}

// ---------- final adapter-up + residual + slice -> f32 out ----------
__global__ __launch_bounds__(128) void k_final(const float* __restrict__ t16, const float* __restrict__ upw,
                                               const float* __restrict__ upb, const float* __restrict__ xf,
                                               float* __restrict__ outx) {
    int rb = blockIdx.x, t = threadIdx.x;
    int b = rb / 129, no = rb % 129;
    int src = b * NT + (no == 0 ? 0 : no + TT);
    __shared__ float tl[16];
    if (t < 16) tl[t] = t16[src * 16 + t];
    __syncthreads();
    for (int d = t; d < DD; d += 128) {
        float acc = 0.f;
#pragma unroll
        for (int c = 0; c < 4; ++c) {
            float4 u = *(const float4*)(upw + d * 16 + c * 4);
            acc += tl[c * 4 + 0] * u.x + tl[c * 4 + 1] * u.y
                 + tl[c * 4 + 2] * u.z + tl[c * 4 + 3] * u.w;
        }
        acc += upb[d];
        outx[(size_t)rb * DD + d] = acc + xf[(size_t)src * DD + d];
    }
}

extern "C" void kernel_launch(void* const* d_in, const int* in_sizes, int n_in,
                              void* d_out, int out_size, void* d_ws, size_t ws_size,
                              hipStream_t stream) {
    const float* x_in    = (const float*)d_in[0];
    const float* center1 = (const float*)d_in[2];
    const float* center2 = (const float*)d_in[3];
    const int*   idx     = (const int*)d_in[5];
    const int*   cidx    = (const int*)d_in[6];
    const float* ln1_g   = (const float*)d_in[9];
    const float* ln1_b   = (const float*)d_in[10];
    const float* ln2_g   = (const float*)d_in[11];
    const float* ln2_b   = (const float*)d_in[12];
    const float* qkv_w   = (const float*)d_in[13];
    const float* proj_w  = (const float*)d_in[14];
    const float* proj_b  = (const float*)d_in[15];
    const float* fc1_w   = (const float*)d_in[16];
    const float* fc1_b   = (const float*)d_in[17];
    const float* fc2_w   = (const float*)d_in[18];
    const float* fc2_b   = (const float*)d_in[19];
    const float* ad_dw   = (const float*)d_in[20];
    const float* ad_db   = (const float*)d_in[21];
    const float* ad_uw   = (const float*)d_in[22];
    const float* ad_ub   = (const float*)d_in[23];
    const float* ad1_dw  = (const float*)d_in[24];
    const float* ad1_db  = (const float*)d_in[25];
    const float* ad1_uw  = (const float*)d_in[26];
    const float* ad1_ub  = (const float*)d_in[27];
    const float* prompt  = (const float*)d_in[28];
    const float* bn_g    = (const float*)d_in[29];
    const float* bn_b    = (const float*)d_in[30];
    const float* bn_mean = (const float*)d_in[31];
    const float* bn_var  = (const float*)d_in[32];
    const float* qkv1_w  = (const float*)d_in[33];
    const float* proj1_w = (const float*)d_in[34];
    const float* proj1_b = (const float*)d_in[35];
    const float* ln3_g   = (const float*)d_in[36];
    const float* ln3_b   = (const float*)d_in[37];

    char* wsb = (char*)d_ws;
    float* XC   = (float*)(wsb + XC_OFF);
    float* VIS  = (float*)(wsb + VIS_OFF);
    bf16*  XNB  = (bf16*)(wsb + XNB_OFF);
    float* XFN  = (float*)(wsb + XFN_OFF);
    float* T16  = (float*)(wsb + T16_OFF);
    bf16*  BIG1 = (bf16*)(wsb + BIG1_OFF);
    bf16*  BIG2 = (bf16*)(wsb + BIG2_OFF);
    float* XFIN = (float*)(wsb + BIG2_OFF);
    bf16*  ATT  = (bf16*)(wsb + ATT_OFF);
    bf16*  WB   = (bf16*)(wsb + WB_OFF);

    float* out_x    = (float*)d_out;
    float* out_attn = out_x + OUT_X;

    // --- weights -> bf16 (graph-safe: every call) ---
    k_wconv<<<(WB_TOTAL / 4 + 255) / 256, 256, 0, stream>>>(qkv_w, proj_w, fc1_w, fc2_w, qkv1_w, proj1_w, WB);

    // --- stage 1 ---
    k_build_xc<<<(M1 * DD + 255) / 256, 256, 0, stream>>>(x_in, prompt, XC);
    k_layernorm<<<M1, 128, 0, stream>>>(XC, XNB, ln1_g, ln1_b, 0);
    mf_gemm<<<dim3(18, 70), 256, 0, stream>>>(XNB, WB + WB_QKV, (const float*)nullptr, (const float*)nullptr, BIG1, M1, 1152, 384, 0);
    k_attn1<<<BB * HH, 256, 0, stream>>>(BIG1, XNB, out_attn);
    mf_gemm<<<dim3(6, 70), 256, 0, stream>>>(XNB, WB + WB_PROJ, proj_b, XC, XC, M1, 384, 384, 0);
    k_layernorm<<<M1, 128, 0, stream>>>(XC, XNB, ln2_g, ln2_b, 0);
    mf_gemm<<<dim3(24, 70), 256, 0, stream>>>(XNB, WB + WB_FC1, fc1_b, (const float*)nullptr, BIG2, M1, 1536, 384, 1);
    mf_gemm<<<dim3(6, 70), 256, 0, stream>>>(BIG2, WB + WB_FC2, fc2_b, (const float*)nullptr, XFN, M1, 384, 1536, 0);
    k_gemm<<<dim3(1, 139), 256, 0, stream>>>(XFN, ad_dw, ad_db, (const float*)nullptr, T16, M1, 16, 384, 1);
    k_ad_combine<<<M1, 128, 0, stream>>>(T16, ad_uw, ad_ub, XFN, XC);

    // --- stage 2 (group attention on 8832 unique rows) ---
    k_layernorm<<<MG, 128, 0, stream>>>(XC, XNB, ln3_g, ln3_b, 1);
    mf_gemm<<<dim3(18, 69), 256, 0, stream>>>(XNB, WB + WB_QKV1, (const float*)nullptr, (const float*)nullptr, BIG1, MG, 1152, 384, 0);
    k_attn2<<<NGRP, 64, 0, stream>>>(BIG1, idx, BIG2);
    mf_gemm<<<dim3(6, 256), 256, 0, stream>>>(BIG2, WB + WB_PROJ1, proj1_b, (const float*)nullptr, ATT, NGRP * 16, 384, 384, 0);
    k_groupmax<<<NGRP, 128, 0, stream>>>(ATT, XC, idx, cidx, bn_g, bn_b, bn_mean, bn_var, VIS);
    k_propagate<<<BB * 128, 128, 0, stream>>>(center1, center2, XC, VIS, XFN);

    // --- final adapter + slice ---
    k_build_xfinal<<<(M1 * DD + 255) / 256, 256, 0, stream>>>(XC, XFN, XFIN);
    k_gemm<<<dim3(1, 139), 256, 0, stream>>>(XFIN, ad1_dw, ad1_db, (const float*)nullptr, T16, M1, 16, 384, 1);
    k_final<<<BB * 129, 128, 0, stream>>>(T16, ad1_uw, ad1_ub, XFIN, out_x);
}

// Round 6
// 498.576 us; speedup vs baseline: 2.4319x; 1.0867x over previous
//
#include <hip/hip_runtime.h>
#include <hip/hip_bf16.h>

typedef __hip_bfloat16 bf16;
typedef __attribute__((ext_vector_type(8))) short short8;
typedef __attribute__((ext_vector_type(4))) float f32x4;

#define DEV static __device__ __forceinline__

DEV float b2f(bf16 v) { return __bfloat162float(v); }
DEV bf16 f2b(float v) { return __float2bfloat16(v); }
DEV unsigned short f2bu(float v) { return __builtin_bit_cast(unsigned short, __float2bfloat16(v)); }
DEV float u2f(unsigned short u) { return __uint_as_float(((unsigned int)u) << 16); }
DEV float gelu(float x) { return 0.5f * x * (1.0f + erff(x * 0.70710678118654752f)); }

// Problem constants
#define BB 64
#define NT 139     // 1 + T + G1
#define DD 384
#define TT 10
#define HH 6
#define GG 138     // G1 + T
#define M1 8896    // BB*NT = 64*139, multiple of 64
#define MG 8832    // BB*GG = 64*138, multiple of 64
#define NGRP 2048  // BB*S
#define SCALE 0.125f

// Workspace byte offsets (proven layout; + bf16 weights block = 90.4 MB)
#define XC_OFF   0UL          // f32 8896x384 residual stream, live whole call
#define VIS_OFF  13664256UL   // f32 2048x384
#define XNB_OFF  16809984UL   // bf16 8896x384: LN out; attn1 o; dead after consumer
#define XFN_OFF  23642112UL   // f32 8896x384: fc2 out; x_prop
#define T16_OFF  37306368UL   // f32 8896x16
#define BIG1_OFF 37875712UL   // bf16 8896x1152: qkv / qkv1
#define BIG2_OFF 58372096UL   // bf16 8896x1536 fc1h / bf16 32768x384 o1 / f32 x_final
#define ATT_OFF  XNB_OFF      // bf16 32768x384 proj1 out (overlays dead XNB..BIG1 prefix)
#define WB_OFF   85700608UL   // bf16 2359296: pre-converted weights

// bf16 weight block element offsets
#define WB_QKV   0
#define WB_PROJ  442368
#define WB_FC1   589824
#define WB_FC2   1179648
#define WB_QKV1  1769472
#define WB_PROJ1 2211840
#define WB_TOTAL 2359296

#define OUT_X 3170304  // 64*129*384

DEV float4 ld4(const float* p) { return *(const float4*)p; }
DEV float4 ld4(const bf16* p) {
    ushort4 u = *(const ushort4*)p;
    return make_float4(u2f(u.x), u2f(u.y), u2f(u.z), u2f(u.w));
}
DEV void stc(float* p, float v) { *p = v; }
DEV void stc(bf16* p, float v) { *p = f2b(v); }

// ---------- weights f32 -> bf16 (once per call) ----------
__global__ __launch_bounds__(256) void k_wconv(const float* __restrict__ w0, const float* __restrict__ w1,
                                               const float* __restrict__ w2, const float* __restrict__ w3,
                                               const float* __restrict__ w4, const float* __restrict__ w5,
                                               bf16* __restrict__ dst) {
    int i4 = (blockIdx.x * 256 + threadIdx.x) * 4;
    if (i4 >= WB_TOTAL) return;
    const float* s; int off;
    if (i4 < WB_PROJ)       { s = w0; off = WB_QKV; }
    else if (i4 < WB_FC1)   { s = w1; off = WB_PROJ; }
    else if (i4 < WB_FC2)   { s = w2; off = WB_FC1; }
    else if (i4 < WB_QKV1)  { s = w3; off = WB_FC2; }
    else if (i4 < WB_PROJ1) { s = w4; off = WB_QKV1; }
    else                    { s = w5; off = WB_PROJ1; }
    float4 v = *(const float4*)(s + (i4 - off));
    ushort4 u;
    u.x = f2bu(v.x); u.y = f2bu(v.y); u.z = f2bu(v.z); u.w = f2bu(v.w);
    *(ushort4*)((unsigned short*)dst + i4) = u;
}

// ---------- concat: xc = [x[:, :1], prompt, x[:, 1:]] ----------
__global__ __launch_bounds__(256) void k_build_xc(const float* __restrict__ x,
                                                  const float* __restrict__ pe,
                                                  float* __restrict__ xc) {
    int i = blockIdx.x * 256 + threadIdx.x;
    if (i >= M1 * DD) return;
    int d = i % DD, r = i / DD, n = r % NT, b = r / NT;
    float v;
    if (n == 0)        v = x[(b * 129) * DD + d];
    else if (n <= TT)  v = pe[(n - 1) * DD + d];
    else               v = x[(b * 129 + n - TT) * DD + d];
    xc[i] = v;
}

// ---------- layernorm f32 -> bf16 (mode 1: gather row (r/138)*139+1+(r%138)) ----------
__global__ __launch_bounds__(128) void k_layernorm(const float* __restrict__ src, bf16* __restrict__ dst,
                                                   const float* __restrict__ g, const float* __restrict__ bta,
                                                   int mode) {
    int r = blockIdx.x;
    int srow = r;
    if (mode) srow = (r / GG) * NT + 1 + (r % GG);
    const float* p = src + (size_t)srow * DD;
    int t = threadIdx.x;
    float v0 = p[t], v1 = p[t + 128], v2 = p[t + 256];
    __shared__ float red[4];
    float s = v0 + v1 + v2;
    for (int off = 32; off; off >>= 1) s += __shfl_down(s, off, 64);
    if ((t & 63) == 0) red[t >> 6] = s;
    __syncthreads();
    float mean = (red[0] + red[1]) * (1.0f / 384.0f);
    float d0 = v0 - mean, d1 = v1 - mean, d2 = v2 - mean;
    float s2 = d0 * d0 + d1 * d1 + d2 * d2;
    for (int off = 32; off; off >>= 1) s2 += __shfl_down(s2, off, 64);
    if ((t & 63) == 0) red[2 + (t >> 6)] = s2;
    __syncthreads();
    float rstd = rsqrtf((red[2] + red[3]) * (1.0f / 384.0f) + 1e-5f);
    bf16* q = dst + (size_t)r * DD;
    q[t]       = f2b(d0 * rstd * g[t]       + bta[t]);
    q[t + 128] = f2b(d1 * rstd * g[t + 128] + bta[t + 128]);
    q[t + 256] = f2b(d2 * rstd * g[t + 256] + bta[t + 256]);
}

// ---------- MFMA GEMM: C[M,N] = act(A[M,K]bf16 @ W[N,K]^T bf16 + bias) (+res) ----------
// BM=64 BN=64 BK=64, 4 waves (2x2) each 32x32 via 2x2x(2 ks) 16x16x32 MFMAs.
// 2-stage register prefetch: load tile k+1 to regs while computing tile k from LDS.
// Requires: M % 64 == 0 (true for all call sites), N % 64 == 0, K % 64 == 0.
template <typename TC>
__global__ __launch_bounds__(256) void mf_gemm(const bf16* __restrict__ A, const bf16* __restrict__ W,
                                               const float* __restrict__ bias, const float* __restrict__ res,
                                               TC* __restrict__ C, int M, int N, int K, int act) {
    __shared__ bf16 As[64][72];
    __shared__ bf16 Ws[64][72];
    int t = threadIdx.x;
    int m0 = blockIdx.y * 64, n0 = blockIdx.x * 64;
    int lane = t & 63, wv = t >> 6;
    int wm = (wv >> 1) * 32, wn = (wv & 1) * 32;
    int fr = lane & 15, fq = lane >> 4;
    int sr = t >> 2, sc = (t & 3) * 16;   // staging: 4 thr/row, 32B (2 x uint4) each
    const bf16* pa = A + (size_t)(m0 + sr) * K + sc;
    const bf16* pw = W + (size_t)(n0 + sr) * K + sc;
    uint4 ra0 = *(const uint4*)pa;
    uint4 ra1 = *(const uint4*)(pa + 8);
    uint4 rw0 = *(const uint4*)pw;
    uint4 rw1 = *(const uint4*)(pw + 8);
    f32x4 acc[2][2] = {};
    int k0 = 0;
    for (;;) {
        *(uint4*)&As[sr][sc] = ra0; *(uint4*)&As[sr][sc + 8] = ra1;
        *(uint4*)&Ws[sr][sc] = rw0; *(uint4*)&Ws[sr][sc + 8] = rw1;
        __syncthreads();
        k0 += 64;
        bool more = (k0 < K);
        if (more) {
            ra0 = *(const uint4*)(pa + k0); ra1 = *(const uint4*)(pa + k0 + 8);
            rw0 = *(const uint4*)(pw + k0); rw1 = *(const uint4*)(pw + k0 + 8);
        }
#pragma unroll
        for (int ks = 0; ks < 2; ++ks) {
            short8 a0 = *(const short8*)&As[wm + fr][ks * 32 + fq * 8];
            short8 a1 = *(const short8*)&As[wm + 16 + fr][ks * 32 + fq * 8];
            short8 b0 = *(const short8*)&Ws[wn + fr][ks * 32 + fq * 8];
            short8 b1 = *(const short8*)&Ws[wn + 16 + fr][ks * 32 + fq * 8];
            acc[0][0] = __builtin_amdgcn_mfma_f32_16x16x32_bf16(a0, b0, acc[0][0], 0, 0, 0);
            acc[0][1] = __builtin_amdgcn_mfma_f32_16x16x32_bf16(a0, b1, acc[0][1], 0, 0, 0);
            acc[1][0] = __builtin_amdgcn_mfma_f32_16x16x32_bf16(a1, b0, acc[1][0], 0, 0, 0);
            acc[1][1] = __builtin_amdgcn_mfma_f32_16x16x32_bf16(a1, b1, acc[1][1], 0, 0, 0);
        }
        if (!more) break;
        __syncthreads();
    }
#pragma unroll
    for (int i = 0; i < 2; ++i) {
#pragma unroll
        for (int r = 0; r < 4; ++r) {
            int row = m0 + wm + i * 16 + fq * 4 + r;
            size_t ro = (size_t)row * N;
#pragma unroll
            for (int j = 0; j < 2; ++j) {
                int col = n0 + wn + j * 16 + fr;
                float c = acc[i][j][r];
                if (bias) c += bias[col];
                if (act == 1) c = gelu(c);
                if (res) c += res[ro + col];
                stc(&C[ro + col], c);
            }
        }
    }
}

// ---------- small fp32 GEMM (N=16 adapters) ----------
#define BM 64
#define BN 64
#define BKK 16
template <typename TA, typename TC>
__global__ __launch_bounds__(256) void k_gemm(const TA* __restrict__ A, const float* __restrict__ W,
                                              const float* __restrict__ bias, const float* __restrict__ res,
                                              TC* __restrict__ C, int M, int N, int K, int act) {
    __shared__ float As[BKK][BM + 4];
    __shared__ float Wsm[BKK][BN + 4];
    int t = threadIdx.x;
    int tx = t & 15, ty = t >> 4;
    int m0 = blockIdx.y * BM, n0 = blockIdx.x * BN;
    int lr = t >> 2;
    int lk = (t & 3) * 4;
    float acc[4][4] = {};
    for (int k0 = 0; k0 < K; k0 += BKK) {
        float4 av = ld4(A + (size_t)(m0 + lr) * K + k0 + lk);
        As[lk + 0][lr] = av.x; As[lk + 1][lr] = av.y;
        As[lk + 2][lr] = av.z; As[lk + 3][lr] = av.w;
        int wrr = n0 + lr;
        float4 wv = make_float4(0.f, 0.f, 0.f, 0.f);
        if (wrr < N) wv = ld4(W + (size_t)wrr * K + k0 + lk);
        Wsm[lk + 0][lr] = wv.x; Wsm[lk + 1][lr] = wv.y;
        Wsm[lk + 2][lr] = wv.z; Wsm[lk + 3][lr] = wv.w;
        __syncthreads();
#pragma unroll
        for (int k = 0; k < BKK; ++k) {
            float a0 = As[k][ty * 4 + 0], a1 = As[k][ty * 4 + 1];
            float a2 = As[k][ty * 4 + 2], a3 = As[k][ty * 4 + 3];
            float b0 = Wsm[k][tx * 4 + 0], b1 = Wsm[k][tx * 4 + 1];
            float b2 = Wsm[k][tx * 4 + 2], b3 = Wsm[k][tx * 4 + 3];
            acc[0][0] += a0 * b0; acc[0][1] += a0 * b1; acc[0][2] += a0 * b2; acc[0][3] += a0 * b3;
            acc[1][0] += a1 * b0; acc[1][1] += a1 * b1; acc[1][2] += a1 * b2; acc[1][3] += a1 * b3;
            acc[2][0] += a2 * b0; acc[2][1] += a2 * b1; acc[2][2] += a2 * b2; acc[2][3] += a2 * b3;
            acc[3][0] += a3 * b0; acc[3][1] += a3 * b1; acc[3][2] += a3 * b2; acc[3][3] += a3 * b3;
        }
        __syncthreads();
    }
#pragma unroll
    for (int i = 0; i < 4; ++i) {
        int m = m0 + ty * 4 + i;
        size_t ro = (size_t)m * N;
#pragma unroll
        for (int j = 0; j < 4; ++j) {
            int n = n0 + tx * 4 + j;
            if (n < N) {
                float c = acc[i][j];
                if (bias) c += bias[n];
                if (act == 1) c = gelu(c);
                if (res) c += res[ro + n];
                stc(&C[ro + n], c);
            }
        }
    }
}

// ---------- stage-1 attention (MFMA): one block per (b,h) ----------
__global__ __launch_bounds__(256) void k_attn1(const bf16* __restrict__ qkv, bf16* __restrict__ o_out,
                                               float* __restrict__ attn_out) {
    int bh = blockIdx.x;
    int b = bh / HH, h = bh % HH;
    __shared__ unsigned short Kl[144][72];
    __shared__ unsigned short Vt[64][160];
    __shared__ unsigned short Pl[4][16][160];
    int t = threadIdx.x;
    int lane = t & 63, wv = t >> 6;
    int fr = lane & 15, fq = lane >> 4;
    const unsigned short* q16 = (const unsigned short*)qkv;
    size_t base = (size_t)b * NT * 1152;

    uint4 z4 = make_uint4(0, 0, 0, 0);
    for (int i = t * 8; i < 64 * 160; i += 2048) *(uint4*)(&Vt[0][0] + i) = z4;
    for (int i = t * 8; i < 4 * 16 * 160; i += 2048) *(uint4*)(&Pl[0][0][0] + i) = z4;
    for (int i = t; i < 144 * 8; i += 256) {
        int row = i >> 3, ch = (i & 7) * 8;
        uint4 v = z4;
        if (row < NT) v = *(const uint4*)(q16 + base + row * 1152 + 384 + h * 64 + ch);
        *(uint4*)&Kl[row][ch] = v;
    }
    for (int i = t; i < NT * 16; i += 256) {
        int m = i >> 4, dq = (i & 15) * 4;
        ushort4 v = *(const ushort4*)(q16 + base + m * 1152 + 768 + h * 64 + dq);
        Vt[dq + 0][m] = v.x; Vt[dq + 1][m] = v.y;
        Vt[dq + 2][m] = v.z; Vt[dq + 3][m] = v.w;
    }
    __syncthreads();

    for (int nt = wv; nt < 9; nt += 4) {
        int n0 = nt * 16;
        int arow = n0 + fr; if (arow > NT - 1) arow = NT - 1;
        const unsigned short* qp = q16 + base + (size_t)arow * 1152 + h * 64 + fq * 8;
        short8 a0 = *(const short8*)qp;
        short8 a1 = *(const short8*)(qp + 32);
        f32x4 s[9] = {};
#pragma unroll
        for (int mt = 0; mt < 9; ++mt) {
            short8 b0 = *(const short8*)&Kl[mt * 16 + fr][fq * 8];
            short8 b1 = *(const short8*)&Kl[mt * 16 + fr][32 + fq * 8];
            s[mt] = __builtin_amdgcn_mfma_f32_16x16x32_bf16(a0, b0, s[mt], 0, 0, 0);
            s[mt] = __builtin_amdgcn_mfma_f32_16x16x32_bf16(a1, b1, s[mt], 0, 0, 0);
        }
#pragma unroll
        for (int r = 0; r < 4; ++r) {
            float e[9];
            float mx = -1e30f;
#pragma unroll
            for (int mt = 0; mt < 9; ++mt) {
                int col = mt * 16 + fr;
                float v = (col < NT) ? s[mt][r] * SCALE : -1e30f;
                e[mt] = v;
                mx = fmaxf(mx, v);
            }
#pragma unroll
            for (int off = 1; off < 16; off <<= 1) mx = fmaxf(mx, __shfl_xor(mx, off, 64));
            float sm = 0.f;
#pragma unroll
            for (int mt = 0; mt < 9; ++mt) { e[mt] = __expf(e[mt] - mx); sm += e[mt]; }
#pragma unroll
            for (int off = 1; off < 16; off <<= 1) sm += __shfl_xor(sm, off, 64);
            float inv = 1.0f / sm;
            int n = n0 + fq * 4 + r;
            bool nv = n < NT;
            size_t ab = ((size_t)(b * HH + h) * NT + n) * NT;
#pragma unroll
            for (int mt = 0; mt < 9; ++mt) {
                float p = e[mt] * inv;
                int col = mt * 16 + fr;
                if (nv && col < NT) attn_out[ab + col] = p;
                Pl[wv][fq * 4 + r][col] = f2bu(p);
            }
        }
        __syncthreads();
        f32x4 oac[4] = {};
#pragma unroll
        for (int ks = 0; ks < 5; ++ks) {
            short8 ap = *(const short8*)&Pl[wv][fr][ks * 32 + fq * 8];
#pragma unroll
            for (int dt = 0; dt < 4; ++dt) {
                short8 bv = *(const short8*)&Vt[dt * 16 + fr][ks * 32 + fq * 8];
                oac[dt] = __builtin_amdgcn_mfma_f32_16x16x32_bf16(ap, bv, oac[dt], 0, 0, 0);
            }
        }
#pragma unroll
        for (int dt = 0; dt < 4; ++dt)
#pragma unroll
            for (int r = 0; r < 4; ++r) {
                int n = n0 + fq * 4 + r;
                if (n < NT)
                    o_out[((size_t)(b * NT + n)) * DD + h * 64 + dt * 16 + fr] = f2b(oac[dt][r]);
            }
    }
}

// ---------- stage-2 per-group attention (MFMA): one wave per group ----------
__global__ __launch_bounds__(64) void k_attn2(const bf16* __restrict__ qkv, const int* __restrict__ idx,
                                              bf16* __restrict__ o1) {
    int g = blockIdx.x;
    __shared__ unsigned short Vt2[64][40];
    __shared__ unsigned short P2[16][40];
    __shared__ int ridx[16];
    int t = threadIdx.x;
    int fr = t & 15, fq = t >> 4;
    const unsigned short* q16 = (const unsigned short*)qkv;
    if (t < 16) ridx[t] = idx[g * 16 + t];
    uint4 z4 = make_uint4(0, 0, 0, 0);
    for (int i = t * 8; i < 64 * 40; i += 512) *(uint4*)(&Vt2[0][0] + i) = z4;
    for (int i = t * 8; i < 16 * 40; i += 512) *(uint4*)(&P2[0][0] + i) = z4;
    __syncthreads();
    size_t qb = (size_t)ridx[fr] * 1152;
    for (int h = 0; h < HH; ++h) {
        for (int i = t; i < 256; i += 64) {
            int m = i >> 4, dq = (i & 15) * 4;
            ushort4 v = *(const ushort4*)(q16 + (size_t)ridx[m] * 1152 + 768 + h * 64 + dq);
            Vt2[dq + 0][m] = v.x; Vt2[dq + 1][m] = v.y;
            Vt2[dq + 2][m] = v.z; Vt2[dq + 3][m] = v.w;
        }
        __syncthreads();
        const unsigned short* qp = q16 + qb + h * 64 + fq * 8;
        const unsigned short* kp = q16 + qb + 384 + h * 64 + fq * 8;
        short8 a0 = *(const short8*)qp;
        short8 a1 = *(const short8*)(qp + 32);
        short8 b0 = *(const short8*)kp;
        short8 b1 = *(const short8*)(kp + 32);
        f32x4 s = {};
        s = __builtin_amdgcn_mfma_f32_16x16x32_bf16(a0, b0, s, 0, 0, 0);
        s = __builtin_amdgcn_mfma_f32_16x16x32_bf16(a1, b1, s, 0, 0, 0);
#pragma unroll
        for (int r = 0; r < 4; ++r) {
            float v = s[r] * SCALE;
            float mx = v;
#pragma unroll
            for (int off = 1; off < 16; off <<= 1) mx = fmaxf(mx, __shfl_xor(mx, off, 64));
            float e = __expf(v - mx), sm = e;
#pragma unroll
            for (int off = 1; off < 16; off <<= 1) sm += __shfl_xor(sm, off, 64);
            P2[fq * 4 + r][fr] = f2bu(e / sm);
        }
        __syncthreads();
        short8 ap = *(const short8*)&P2[fr][fq * 8];
        f32x4 oac[4] = {};
#pragma unroll
        for (int dt = 0; dt < 4; ++dt) {
            short8 bv = *(const short8*)&Vt2[dt * 16 + fr][fq * 8];
            oac[dt] = __builtin_amdgcn_mfma_f32_16x16x32_bf16(ap, bv, oac[dt], 0, 0, 0);
        }
#pragma unroll
        for (int dt = 0; dt < 4; ++dt)
#pragma unroll
            for (int r = 0; r < 4; ++r)
                o1[((size_t)(g * 16 + fq * 4 + r)) * DD + h * 64 + dt * 16 + fr] = f2b(oac[dt][r]);
        __syncthreads();
    }
}

// ---------- adapter combine: xc += 0.7*(t16 @ up^T + up_b) + xfn ----------
__global__ __launch_bounds__(128) void k_ad_combine(const float* __restrict__ t16, const float* __restrict__ upw,
                                                    const float* __restrict__ upb, const float* __restrict__ xfn,
                                                    float* xc) {
    int r = blockIdx.x, t = threadIdx.x;
    __shared__ float tl[16];
    if (t < 16) tl[t] = t16[r * 16 + t];
    __syncthreads();
    for (int d = t; d < DD; d += 128) {
        float acc = 0.f;
#pragma unroll
        for (int c = 0; c < 4; ++c) {
            float4 u = *(const float4*)(upw + d * 16 + c * 4);
            acc += tl[c * 4 + 0] * u.x + tl[c * 4 + 1] * u.y
                 + tl[c * 4 + 2] * u.z + tl[c * 4 + 3] * u.w;
        }
        acc += upb[d];
        size_t i = (size_t)r * DD + d;
        xc[i] += 0.7f * acc + xfn[i];
    }
}

// ---------- group residual + max + BN + GELU + centers -> vis ----------
__global__ __launch_bounds__(128) void k_groupmax(const bf16* __restrict__ att, const float* __restrict__ xc,
                                                  const int* __restrict__ idx, const int* __restrict__ cidx,
                                                  const float* __restrict__ bg, const float* __restrict__ bb,
                                                  const float* __restrict__ bmean, const float* __restrict__ bvar,
                                                  float* __restrict__ vis) {
    int g = blockIdx.x, t = threadIdx.x;
    __shared__ int rows[16];
    __shared__ int crow;
    if (t < 16) { int r = idx[g * 16 + t]; rows[t] = (r / GG) * NT + 1 + (r % GG); }
    if (t == 16) { int r = cidx[g]; crow = (r / GG) * NT + 1 + (r % GG); }
    __syncthreads();
    for (int d = t; d < DD; d += 128) {
        float m = -INFINITY;
#pragma unroll
        for (int j = 0; j < 16; ++j) {
            float v = b2f(att[((size_t)(g * 16 + j)) * DD + d]) + xc[(size_t)rows[j] * DD + d];
            m = fmaxf(m, v);
        }
        float bn = (m - bmean[d]) * rsqrtf(bvar[d] + 1e-5f) * bg[d] + bb[d];
        bn = gelu(bn);
        vis[(size_t)g * DD + d] = bn + 0.3f * xc[(size_t)crow * DD + d];
    }
}

// ---------- propagate ----------
__global__ __launch_bounds__(128) void k_propagate(const float* __restrict__ c1, const float* __restrict__ c2,
                                                   const float* __restrict__ xc, const float* __restrict__ vis,
                                                   float* __restrict__ xp) {
    int blk = blockIdx.x;
    int b = blk >> 7, i = blk & 127;
    int t = threadIdx.x;
    __shared__ float wl[32];
    __shared__ float wsum;
    if (t < 32) {
        float dx = c1[(b * 128 + i) * 3 + 0] - c2[(b * 32 + t) * 3 + 0];
        float dy = c1[(b * 128 + i) * 3 + 1] - c2[(b * 32 + t) * 3 + 1];
        float dz = c1[(b * 128 + i) * 3 + 2] - c2[(b * 32 + t) * 3 + 2];
        wl[t] = 1.0f / (dx * dx + dy * dy + dz * dz + 1e-8f);
    }
    __syncthreads();
    if (t == 0) {
        float s = 0.f;
        for (int j = 0; j < 32; ++j) s += wl[j];
        wsum = s;
    }
    __syncthreads();
    float sc = 0.3f / wsum;
    for (int d = t; d < DD; d += 128) {
        float acc = 0.f;
#pragma unroll 8
        for (int j = 0; j < 32; ++j) acc += wl[j] * vis[((size_t)(b * 32 + j)) * DD + d];
        xp[((size_t)(b * 128 + i)) * DD + d] = xc[((size_t)(b * NT + 11 + i)) * DD + d] + sc * acc;
    }
}

// ---------- build x_final = [cls, prompt, x_prop] ----------
__global__ __launch_bounds__(256) void k_build_xfinal(const float* __restrict__ xc, const float* __restrict__ xp,
                                                      float* __restrict__ xf) {
    int i = blockIdx.x * 256 + threadIdx.x;
    if (i >= M1 * DD) return;
    int d = i % DD, r = i / DD, n = r % NT, b = r / NT;
    xf[i] = (n < 11) ? xc[i] : xp[((size_t)(b * 128 + n - 11)) * DD + d];
}

// ---------- final adapter-up + residual + slice -> f32 out ----------
__global__ __launch_bounds__(128) void k_final(const float* __restrict__ t16, const float* __restrict__ upw,
                                               const float* __restrict__ upb, const float* __restrict__ xf,
                                               float* __restrict__ outx) {
    int rb = blockIdx.x, t = threadIdx.x;
    int b = rb / 129, no = rb % 129;
    int src = b * NT + (no == 0 ? 0 : no + TT);
    __shared__ float tl[16];
    if (t < 16) tl[t] = t16[src * 16 + t];
    __syncthreads();
    for (int d = t; d < DD; d += 128) {
        float acc = 0.f;
#pragma unroll
        for (int c = 0; c < 4; ++c) {
            float4 u = *(const float4*)(upw + d * 16 + c * 4);
            acc += tl[c * 4 + 0] * u.x + tl[c * 4 + 1] * u.y
                 + tl[c * 4 + 2] * u.z + tl[c * 4 + 3] * u.w;
        }
        acc += upb[d];
        outx[(size_t)rb * DD + d] = acc + xf[(size_t)src * DD + d];
    }
}

extern "C" void kernel_launch(void* const* d_in, const int* in_sizes, int n_in,
                              void* d_out, int out_size, void* d_ws, size_t ws_size,
                              hipStream_t stream) {
    const float* x_in    = (const float*)d_in[0];
    const float* center1 = (const float*)d_in[2];
    const float* center2 = (const float*)d_in[3];
    const int*   idx     = (const int*)d_in[5];
    const int*   cidx    = (const int*)d_in[6];
    const float* ln1_g   = (const float*)d_in[9];
    const float* ln1_b   = (const float*)d_in[10];
    const float* ln2_g   = (const float*)d_in[11];
    const float* ln2_b   = (const float*)d_in[12];
    const float* qkv_w   = (const float*)d_in[13];
    const float* proj_w  = (const float*)d_in[14];
    const float* proj_b  = (const float*)d_in[15];
    const float* fc1_w   = (const float*)d_in[16];
    const float* fc1_b   = (const float*)d_in[17];
    const float* fc2_w   = (const float*)d_in[18];
    const float* fc2_b   = (const float*)d_in[19];
    const float* ad_dw   = (const float*)d_in[20];
    const float* ad_db   = (const float*)d_in[21];
    const float* ad_uw   = (const float*)d_in[22];
    const float* ad_ub   = (const float*)d_in[23];
    const float* ad1_dw  = (const float*)d_in[24];
    const float* ad1_db  = (const float*)d_in[25];
    const float* ad1_uw  = (const float*)d_in[26];
    const float* ad1_ub  = (const float*)d_in[27];
    const float* prompt  = (const float*)d_in[28];
    const float* bn_g    = (const float*)d_in[29];
    const float* bn_b    = (const float*)d_in[30];
    const float* bn_mean = (const float*)d_in[31];
    const float* bn_var  = (const float*)d_in[32];
    const float* qkv1_w  = (const float*)d_in[33];
    const float* proj1_w = (const float*)d_in[34];
    const float* proj1_b = (const float*)d_in[35];
    const float* ln3_g   = (const float*)d_in[36];
    const float* ln3_b   = (const float*)d_in[37];

    char* wsb = (char*)d_ws;
    float* XC   = (float*)(wsb + XC_OFF);
    float* VIS  = (float*)(wsb + VIS_OFF);
    bf16*  XNB  = (bf16*)(wsb + XNB_OFF);
    float* XFN  = (float*)(wsb + XFN_OFF);
    float* T16  = (float*)(wsb + T16_OFF);
    bf16*  BIG1 = (bf16*)(wsb + BIG1_OFF);
    bf16*  BIG2 = (bf16*)(wsb + BIG2_OFF);
    float* XFIN = (float*)(wsb + BIG2_OFF);
    bf16*  ATT  = (bf16*)(wsb + ATT_OFF);
    bf16*  WB   = (bf16*)(wsb + WB_OFF);

    float* out_x    = (float*)d_out;
    float* out_attn = out_x + OUT_X;

    // --- weights -> bf16 (graph-safe: every call) ---
    k_wconv<<<(WB_TOTAL / 4 + 255) / 256, 256, 0, stream>>>(qkv_w, proj_w, fc1_w, fc2_w, qkv1_w, proj1_w, WB);

    // --- stage 1 ---
    k_build_xc<<<(M1 * DD + 255) / 256, 256, 0, stream>>>(x_in, prompt, XC);
    k_layernorm<<<M1, 128, 0, stream>>>(XC, XNB, ln1_g, ln1_b, 0);
    mf_gemm<<<dim3(18, 139), 256, 0, stream>>>(XNB, WB + WB_QKV, (const float*)nullptr, (const float*)nullptr, BIG1, M1, 1152, 384, 0);
    k_attn1<<<BB * HH, 256, 0, stream>>>(BIG1, XNB, out_attn);
    mf_gemm<<<dim3(6, 139), 256, 0, stream>>>(XNB, WB + WB_PROJ, proj_b, XC, XC, M1, 384, 384, 0);
    k_layernorm<<<M1, 128, 0, stream>>>(XC, XNB, ln2_g, ln2_b, 0);
    mf_gemm<<<dim3(24, 139), 256, 0, stream>>>(XNB, WB + WB_FC1, fc1_b, (const float*)nullptr, BIG2, M1, 1536, 384, 1);
    mf_gemm<<<dim3(6, 139), 256, 0, stream>>>(BIG2, WB + WB_FC2, fc2_b, (const float*)nullptr, XFN, M1, 384, 1536, 0);
    k_gemm<<<dim3(1, 139), 256, 0, stream>>>(XFN, ad_dw, ad_db, (const float*)nullptr, T16, M1, 16, 384, 1);
    k_ad_combine<<<M1, 128, 0, stream>>>(T16, ad_uw, ad_ub, XFN, XC);

    // --- stage 2 (group attention on 8832 unique rows) ---
    k_layernorm<<<MG, 128, 0, stream>>>(XC, XNB, ln3_g, ln3_b, 1);
    mf_gemm<<<dim3(18, 138), 256, 0, stream>>>(XNB, WB + WB_QKV1, (const float*)nullptr, (const float*)nullptr, BIG1, MG, 1152, 384, 0);
    k_attn2<<<NGRP, 64, 0, stream>>>(BIG1, idx, BIG2);
    mf_gemm<<<dim3(6, 512), 256, 0, stream>>>(BIG2, WB + WB_PROJ1, proj1_b, (const float*)nullptr, ATT, NGRP * 16, 384, 384, 0);
    k_groupmax<<<NGRP, 128, 0, stream>>>(ATT, XC, idx, cidx, bn_g, bn_b, bn_mean, bn_var, VIS);
    k_propagate<<<BB * 128, 128, 0, stream>>>(center1, center2, XC, VIS, XFN);

    // --- final adapter + slice ---
    k_build_xfinal<<<(M1 * DD + 255) / 256, 256, 0, stream>>>(XC, XFN, XFIN);
    k_gemm<<<dim3(1, 139), 256, 0, stream>>>(XFIN, ad1_dw, ad1_db, (const float*)nullptr, T16, M1, 16, 384, 1);
    k_final<<<BB * 129, 128, 0, stream>>>(T16, ad1_uw, ad1_ub, XFIN, out_x);
}